// Round 18
// baseline (751.816 us; speedup 1.0000x reference)
//
#include <hip/hip_runtime.h>
#include <hip/hip_bf16.h>

typedef unsigned short u16;
typedef __bf16 bf16x8 __attribute__((ext_vector_type(8)));
typedef float floatx4 __attribute__((ext_vector_type(4)));
typedef __attribute__((address_space(3))) const char* lds_cp;

#define MFMA16(a, b, c) __builtin_amdgcn_mfma_f32_16x16x32_bf16((a), (b), (c), 0, 0, 0)

__device__ __forceinline__ u16 f2bf(float f) {
  __bf16 h = (__bf16)f;
  return __builtin_bit_cast(u16, h);
}
__device__ __forceinline__ float bf2f(u16 v) {
  unsigned int u = ((unsigned int)v) << 16;
  return __builtin_bit_cast(float, u);
}

__device__ __forceinline__ void async_copy16(const void* g, void* l) {
  __builtin_amdgcn_global_load_lds(
      (const __attribute__((address_space(1))) unsigned int*)g,
      (__attribute__((address_space(3))) unsigned int*)l, 16, 0, 0);
}

// inline-asm LDS reads: opaque to the waitcnt legalizer (R11-verified +24%).
// Pair with explicit lgkmcnt(0) + sched_barrier(0) before consuming (rule #18).
__device__ __forceinline__ bf16x8 ds_read16(lds_cp p) {
  bf16x8 r;
  asm volatile("ds_read_b128 %0, %1" : "=v"(r) : "v"(p));
  return r;
}
// base + compile-time offset variant: zero per-read VALU address math (R13, +8%).
template <int IMM>
__device__ __forceinline__ bf16x8 ds_read16o(lds_cp p) {
  bf16x8 r;
  asm volatile("ds_read_b128 %0, %1 offset:%2" : "=v"(r) : "v"(p), "i"(IMM));
  return r;
}

// ---------------------------------------------------------------- sentinel
__global__ void sentinel_k(float* out, float v) {
  if (threadIdx.x == 0 && blockIdx.x == 0) out[0] = v;
}

// ---------------------------------------------------------------- cast x -> bf16
__global__ __launch_bounds__(256) void cast_k(const float* __restrict__ in,
                                              u16* __restrict__ out, size_t n) {
  size_t i = ((size_t)blockIdx.x * 256 + threadIdx.x) * 8;
  if (i >= n) return;
  float4 a = *(const float4*)&in[i];
  float4 b = *(const float4*)&in[i + 4];
  union { u16 q[8]; uint4 u; } pk;
  pk.q[0] = f2bf(a.x); pk.q[1] = f2bf(a.y); pk.q[2] = f2bf(a.z); pk.q[3] = f2bf(a.w);
  pk.q[4] = f2bf(b.x); pk.q[5] = f2bf(b.y); pk.q[6] = f2bf(b.z); pk.q[7] = f2bf(b.w);
  *(uint4*)&out[i] = pk.u;
}

// ------------------------------------------- transpose-cast W[K,N] f32 -> Wt[N,K] bf16
__device__ __forceinline__ void tcast_body(const float* __restrict__ W,
                                           u16* __restrict__ Wt, int K, int N,
                                           int bx, int by, int tid) {
  __shared__ __align__(16) u16 T[64][72];
  const int k0 = bx * 64, n0 = by * 64;
  const int r = tid >> 2, cg = (tid & 3) * 16;
#pragma unroll
  for (int j = 0; j < 4; ++j) {
    float4 w = *(const float4*)&W[(size_t)(k0 + r) * N + n0 + cg + j * 4];
    union { u16 q[4]; uint2 u; } pk;
    pk.q[0] = f2bf(w.x); pk.q[1] = f2bf(w.y); pk.q[2] = f2bf(w.z); pk.q[3] = f2bf(w.w);
    *(uint2*)&T[r][cg + j * 4] = pk.u;
  }
  __syncthreads();
  const int n = tid >> 2, kg = (tid & 3) * 16;
#pragma unroll
  for (int j = 0; j < 4; ++j) {
    union { u16 q[4]; uint2 u; } pk;
#pragma unroll
    for (int i = 0; i < 4; ++i) pk.q[i] = T[kg + j * 4 + i][n];
    *(uint2*)&Wt[(size_t)(n0 + n) * K + k0 + kg + j * 4] = pk.u;
  }
}

__global__ __launch_bounds__(256) void tcast_k(const float* __restrict__ W,
                                               u16* __restrict__ Wt, int K, int N) {
  tcast_body(W, Wt, K, N, blockIdx.x, blockIdx.y, threadIdx.x);
}

__global__ __launch_bounds__(256) void tcast5_k(
    const float* __restrict__ s0, const float* __restrict__ s1,
    const float* __restrict__ s2, const float* __restrict__ s3,
    const float* __restrict__ s4, u16* __restrict__ d0, u16* __restrict__ d1,
    u16* __restrict__ d2, u16* __restrict__ d3, u16* __restrict__ d4) {
  const float* W;
  u16* Wt;
  switch (blockIdx.z) {
    case 0: W = s0; Wt = d0; break;
    case 1: W = s1; Wt = d1; break;
    case 2: W = s2; Wt = d2; break;
    case 3: W = s3; Wt = d3; break;
    default: W = s4; Wt = d4; break;
  }
  tcast_body(W, Wt, 1024, 1024, blockIdx.x, blockIdx.y, threadIdx.x);
}

// ---------------------------------------------------------------- bias concat
__global__ __launch_bounds__(256) void catbias_k(const float* __restrict__ a,
                                                 const float* __restrict__ b,
                                                 const float* __restrict__ c,
                                                 float* __restrict__ o) {
  int i = blockIdx.x * 256 + threadIdx.x;
  if (i >= 3072) return;
  o[i] = i < 1024 ? a[i] : (i < 2048 ? b[i - 1024] : c[i - 2048]);
}

// -------------------------------- transpose V (stride VS) -> Vt[bh, dk, s] bf16
__global__ __launch_bounds__(256) void tv_k(const u16* __restrict__ V,
                                            u16* __restrict__ Vt, int VS) {
  __shared__ __align__(16) u16 T[64][72];
  const int bh = blockIdx.x, st = blockIdx.y;
  const int b = bh >> 4, h = bh & 15;
  const int s0 = st * 64;
  const int tid = threadIdx.x;
  const int r = tid >> 2, cg = (tid & 3) * 16;
#pragma unroll
  for (int j = 0; j < 2; ++j) {
    uint4 v = *(const uint4*)&V[(size_t)(b * 1024 + s0 + r) * VS + h * 64 + cg + j * 8];
    *(uint4*)&T[r][cg + j * 8] = v;
  }
  __syncthreads();
  const int dk = tid >> 2, sg = (tid & 3) * 16;
#pragma unroll
  for (int j = 0; j < 2; ++j) {
    union { u16 q[8]; uint4 u; } pk;
#pragma unroll
    for (int i = 0; i < 8; ++i) pk.q[i] = T[sg + j * 8 + i][dk];
    *(uint4*)&Vt[(size_t)(bh * 64 + dk) * 1024 + s0 + sg + j * 8] = pk.u;
  }
}

// ============================== 8-phase 256x256 GEMM (R13 schedule, verified) ====
#define LDA4(dst, P, KH, MB)                                          \
  dst[0] = ds_read16o<((MB) + 0) * 1024 + (KH) * 16384 + (P) * 32768>(aB); \
  dst[1] = ds_read16o<((MB) + 1) * 1024 + (KH) * 16384 + (P) * 32768>(aB); \
  dst[2] = ds_read16o<((MB) + 2) * 1024 + (KH) * 16384 + (P) * 32768>(aB); \
  dst[3] = ds_read16o<((MB) + 3) * 1024 + (KH) * 16384 + (P) * 32768>(aB);

#define LDB4(dst, P, KH)                                              \
  dst[0] = ds_read16o<0 * 1024 + (KH) * 16384 + (P) * 32768>(bB);     \
  dst[1] = ds_read16o<1 * 1024 + (KH) * 16384 + (P) * 32768>(bB);     \
  dst[2] = ds_read16o<2 * 1024 + (KH) * 16384 + (P) * 32768>(bB);     \
  dst[3] = ds_read16o<3 * 1024 + (KH) * 16384 + (P) * 32768>(bB);

#define FENCE_MFMA()                        \
  __builtin_amdgcn_s_barrier();             \
  asm volatile("s_waitcnt lgkmcnt(0)");     \
  __builtin_amdgcn_sched_barrier(0);

#define GEMM8_TILE(P)                                                     \
  {                                                                       \
    const int t1 = (t + 1 < NT) ? t + 1 : t + 1 - NT;                     \
    const int t2 = (t + 2 < NT) ? t + 2 : t + 2 - NT;                     \
    bf16x8 a[4], b0[4], b1[4];                                            \
    LDA4(a, P, 0, 0); LDB4(b0, P, 0);                                     \
    stA(t1, 1, (P) ^ 1);                                                  \
    FENCE_MFMA();                                                         \
    mma(a, b0, 0);                                                        \
    __builtin_amdgcn_s_barrier();                                         \
    LDA4(a, P, 1, 0); LDB4(b1, P, 1);                                     \
    stB(t2, 0, P);                                                        \
    FENCE_MFMA();                                                         \
    mma(a, b1, 0);                                                        \
    __builtin_amdgcn_s_barrier();                                         \
    LDA4(a, P, 0, 4);                                                     \
    stB(t2, 1, P);                                                        \
    FENCE_MFMA();                                                         \
    mma(a, b0, 4);                                                        \
    __builtin_amdgcn_s_barrier();                                         \
    LDA4(a, P, 1, 4);                                                     \
    stA(t2, 0, P);                                                        \
    asm volatile("s_waitcnt vmcnt(6)");                                   \
    FENCE_MFMA();                                                         \
    mma(a, b1, 4);                                                        \
    __builtin_amdgcn_s_barrier();                                         \
  }

template <int NF, int ACT, int OBF>
__global__ __launch_bounds__(512, 2) void gemm8_k(const u16* __restrict__ A,
                                                  const u16* __restrict__ Bt,
                                                  const float* __restrict__ bias,
                                                  void* __restrict__ Cout,
                                                  int M, int N, int K, float scale) {
  static_assert(NF == 4, "gemm8_k tuned for NF=4 only");
  __shared__ __align__(16) u16 As[2][2][256 * 32];
  __shared__ __align__(16) u16 Bs[2][2][256 * 32];

  const int tid = threadIdx.x;
  const int lane = tid & 63, wv = tid >> 6;
  const int wm = wv >> 2, wn = wv & 3;
  const int g = lane >> 4, li = lane & 15;
  const int m0 = blockIdx.x * 256, n0 = blockIdx.y * 256;
  const int NT = K >> 6;

  const int srow = lane >> 2;
  const int sk8 = (lane & 3) ^ ((srow >> 1) & 3);
  const size_t abase = (size_t)(m0 + wv * 32 + srow) * K + sk8 * 8;
  const size_t bbase = (size_t)(n0 + wv * 32 + srow) * K + sk8 * 8;

  auto stA = [&](int tt, int kh, int p) {
#pragma unroll
    for (int j = 0; j < 2; ++j)
      async_copy16(A + abase + (size_t)j * 16 * K + tt * 64 + kh * 32,
                   (char*)&As[p][kh][0] + (wv * 2 + j) * 1024);
  };
  auto stB = [&](int tt, int kh, int p) {
#pragma unroll
    for (int j = 0; j < 2; ++j)
      async_copy16(Bt + bbase + (size_t)j * 16 * K + tt * 64 + kh * 32,
                   (char*)&Bs[p][kh][0] + (wv * 2 + j) * 1024);
  };

  const int swz = ((li >> 1) & 3) << 4;
  lds_cp aB = (lds_cp)((const char*)&As[0][0][0] +
                       (((wm * 128 + li) * 64 + g * 16) ^ swz));
  lds_cp bB = (lds_cp)((const char*)&Bs[0][0][0] +
                       (((wn * 64 + li) * 64 + g * 16) ^ swz));

  floatx4 acc[8][4] = {};
  auto mma = [&](bf16x8 (&a)[4], bf16x8 (&b)[4], int mb) {
    __builtin_amdgcn_s_setprio(1);
#pragma unroll
    for (int mf = 0; mf < 4; ++mf)
#pragma unroll
      for (int nf = 0; nf < 4; ++nf)
        acc[mb + mf][nf] = MFMA16(a[mf], b[nf], acc[mb + mf][nf]);
    __builtin_amdgcn_s_setprio(0);
  };

  stB(0, 0, 0); stB(0, 1, 0); stA(0, 0, 0); stA(0, 1, 0);
  stB(1, 0, 1); stB(1, 1, 1); stA(1, 0, 1);
  asm volatile("s_waitcnt vmcnt(6)");
  __builtin_amdgcn_s_barrier();

  for (int tb = 0; tb < NT; tb += 2) {
    { const int t = tb;     GEMM8_TILE(0); }
    { const int t = tb + 1; GEMM8_TILE(1); }
  }
  asm volatile("s_waitcnt vmcnt(0)");

  float bv[4];
#pragma unroll
  for (int nf = 0; nf < 4; ++nf) bv[nf] = bias[n0 + wn * 64 + nf * 16 + li];
#pragma unroll
  for (int mf = 0; mf < 8; ++mf)
#pragma unroll
    for (int nf = 0; nf < 4; ++nf)
#pragma unroll
      for (int i = 0; i < 4; ++i) {
        size_t r = (size_t)m0 + wm * 128 + mf * 16 + g * 4 + i;
        size_t c = (size_t)n0 + wn * 64 + nf * 16 + li;
        float v = (acc[mf][nf][i] + bv[nf]) * scale;
        if (ACT == 1) v = 0.5f * v * (1.0f + erff(v * 0.70710678118654752f));
        if (ACT == 2) v = 1.0f / (1.0f + __expf(-v));
        if (OBF)
          ((u16*)Cout)[r * N + c] = f2bf(v);
        else
          ((float*)Cout)[r * N + c] = v;
      }
}

// ================= 128^2 GEMM, 2-phase counted pipeline (R16, verified) =======
template <int ACT, int OBF>
__global__ __launch_bounds__(256, 2) void gemm2_k(const u16* __restrict__ A,
                                                  const u16* __restrict__ Bt,
                                                  const float* __restrict__ bias,
                                                  void* __restrict__ Cout, int M,
                                                  int N, int K, float scale) {
  __shared__ __align__(16) u16 As[2][128 * 64];
  __shared__ __align__(16) u16 Bs[2][128 * 64];
  const int tid = threadIdx.x;
  const int lane = tid & 63;
  const int wv = tid >> 6;
  const int m0 = blockIdx.x * 128, n0 = blockIdx.y * 128;
  const int wm = (wv >> 1) * 64, wn = (wv & 1) * 64;
  const int NT = K >> 6;

  floatx4 acc[4][4] = {};
  const u16* Ab = A + (size_t)m0 * K;
  const u16* Bb = Bt + (size_t)n0 * K;

  int a_off[4][2], b_off[4][2];
#pragma unroll
  for (int f = 0; f < 4; ++f) {
#pragma unroll
    for (int ks = 0; ks < 2; ++ks) {
      int kk = ks * 32 + ((lane >> 4) << 3);
      int ra = wm + f * 16 + (lane & 15);
      a_off[f][ks] = (ra * 128 + kk * 2) ^ ((ra & 7) << 4);
      int rb = wn + f * 16 + (lane & 15);
      b_off[f][ks] = (rb * 128 + kk * 2) ^ ((rb & 7) << 4);
    }
  }
  const int srow = tid >> 3;
  const int scg = ((tid & 7) ^ (srow & 7)) << 3;

  auto stage = [&](int tt, int p) {
#pragma unroll
    for (int it = 0; it < 4; ++it) {
      int row = it * 32 + srow;
      async_copy16(Ab + (size_t)row * K + tt * 64 + scg,
                   (char*)&As[p][0] + (it * 256 + wv * 64) * 16);
      async_copy16(Bb + (size_t)row * K + tt * 64 + scg,
                   (char*)&Bs[p][0] + (it * 256 + wv * 64) * 16);
    }
  };

  stage(0, 0);
  stage(1, 1);
  asm volatile("s_waitcnt vmcnt(8)");
  __builtin_amdgcn_s_barrier();

  for (int t = 0; t < NT; ++t) {
    const int p = t & 1;
    const int t2 = (t + 2 < NT) ? t + 2 : t + 2 - NT;
    lds_cp aL = (lds_cp)(const char*)&As[p][0];
    lds_cp bL = (lds_cp)(const char*)&Bs[p][0];

    bf16x8 af[4][2], bfr[4][2];
#pragma unroll
    for (int f = 0; f < 4; ++f) {
      af[f][0] = ds_read16(aL + a_off[f][0]);
      af[f][1] = ds_read16(aL + a_off[f][1]);
      bfr[f][0] = ds_read16(bL + b_off[f][0]);
      bfr[f][1] = ds_read16(bL + b_off[f][1]);
    }
    asm volatile("s_waitcnt lgkmcnt(0)");
    __builtin_amdgcn_sched_barrier(0);
    __builtin_amdgcn_s_barrier();

    stage(t2, p);

    __builtin_amdgcn_s_setprio(1);
#pragma unroll
    for (int mi = 0; mi < 4; ++mi) {
#pragma unroll
      for (int ni = 0; ni < 4; ++ni) {
        acc[mi][ni] = MFMA16(af[mi][0], bfr[ni][0], acc[mi][ni]);
        acc[mi][ni] = MFMA16(af[mi][1], bfr[ni][1], acc[mi][ni]);
      }
    }
    __builtin_amdgcn_s_setprio(0);

    asm volatile("s_waitcnt vmcnt(8)");
    __builtin_amdgcn_s_barrier();
  }
  asm volatile("s_waitcnt vmcnt(0)");

  float bv[4];
#pragma unroll
  for (int ni = 0; ni < 4; ++ni) bv[ni] = bias[n0 + wn + ni * 16 + (lane & 15)];
#pragma unroll
  for (int mi = 0; mi < 4; ++mi) {
#pragma unroll
    for (int ni = 0; ni < 4; ++ni) {
#pragma unroll
      for (int i = 0; i < 4; ++i) {
        size_t r = (size_t)m0 + wm + mi * 16 + ((lane >> 4) << 2) + i;
        size_t c = (size_t)n0 + wn + ni * 16 + (lane & 15);
        float v = (acc[mi][ni][i] + bv[ni]) * scale;
        if (ACT == 1) v = 0.5f * v * (1.0f + erff(v * 0.70710678118654752f));
        if (ACT == 2) v = 1.0f / (1.0f + __expf(-v));
        if (OBF)
          ((u16*)Cout)[r * N + c] = f2bf(v);
        else
          ((float*)Cout)[r * N + c] = v;
      }
    }
  }
}

// ---------------------------------------------------------------- flash attention
// R17: MQ=4 (64 q-rows/wave, 256/block) — halves K/V staging+barrier cost per
// MFMA and halves K/V HBM re-reads. Max-free softmax + R12 pipeline.
__global__ __launch_bounds__(256) void attn_k(const u16* __restrict__ Q,
                                              const u16* __restrict__ Kb,
                                              const u16* __restrict__ Vt,
                                              u16* __restrict__ Ob, int QS) {
  __shared__ __align__(16) u16 Ks[2][64 * 64];
  __shared__ __align__(16) u16 Vs[2][64 * 64];
  __shared__ __align__(16) u16 Pl[4][4096];  // 8KB/wave: 64 rows x 128B
  const int qt = blockIdx.x, bh = blockIdx.y;
  const int b = bh >> 4, h = bh & 15;
  const int tid = threadIdx.x;
  const int lane = tid & 63, wv = tid >> 6;
  const int g = lane >> 4, li = lane & 15;
  const float SC = 0.125f * 1.4426950408889634f;  // /sqrt(Dk) * log2(e)

  bf16x8 qf[4][2];
#pragma unroll
  for (int m = 0; m < 4; ++m) {
    int qrow = qt * 256 + wv * 64 + m * 16 + li;
    const u16* qp = Q + ((size_t)(b * 1024 + qrow)) * QS + h * 64 + g * 8;
    qf[m][0] = *(const bf16x8*)qp;
    qf[m][1] = *(const bf16x8*)(qp + 32);
  }

  float l_i[4][4] = {};
  floatx4 o[4][4] = {};

  const int r0 = tid >> 3;
  const int csrc = ((tid & 7) ^ (r0 & 7)) * 8;
  const u16* Kg = Kb + ((size_t)b * 1024) * QS + h * 64;
  const u16* Vg = Vt + ((size_t)bh * 64) * 1024;
  char* Pw = (char*)&Pl[wv][0];

  auto stage = [&](int bi, int kv0) {  // 4 loads/thread
#pragma unroll
    for (int it = 0; it < 2; ++it) {
      int row = it * 32 + r0;
      async_copy16(Kg + (size_t)(kv0 + row) * QS + csrc, &Ks[bi][(it * 256 + wv * 64) * 8]);
      async_copy16(Vg + (size_t)row * 1024 + kv0 + csrc, &Vs[bi][(it * 256 + wv * 64) * 8]);
    }
  };

  stage(0, 0);
  int buf = 0;

  for (int t = 0; t < 16; ++t) {
    if (t < 15) {
      stage(buf ^ 1, (t + 1) * 64);
      asm volatile("s_waitcnt vmcnt(4)");
    } else {
      asm volatile("s_waitcnt vmcnt(0)");
    }
    __builtin_amdgcn_s_barrier();

    const char* kb = (const char*)&Ks[buf][0];
    const char* vb = (const char*)&Vs[buf][0];

    bf16x8 kf[4][2];
#pragma unroll
    for (int n = 0; n < 4; ++n) {
      int krow = n * 16 + li;
      int by0 = (krow * 128 + g * 16) ^ ((krow & 7) << 4);
      int by1 = (krow * 128 + 64 + g * 16) ^ ((krow & 7) << 4);
      kf[n][0] = ds_read16((lds_cp)kb + by0);
      kf[n][1] = ds_read16((lds_cp)kb + by1);
    }
    asm volatile("s_waitcnt lgkmcnt(0)");
    __builtin_amdgcn_sched_barrier(0);
    floatx4 s[4][4];
    __builtin_amdgcn_s_setprio(1);
#pragma unroll
    for (int m = 0; m < 4; ++m)
#pragma unroll
      for (int n = 0; n < 4; ++n) {
        floatx4 z = {0.f, 0.f, 0.f, 0.f};
        s[m][n] = MFMA16(qf[m][0], kf[n][0], z);
        s[m][n] = MFMA16(qf[m][1], kf[n][1], s[m][n]);
      }
    __builtin_amdgcn_s_setprio(0);

#pragma unroll
    for (int m = 0; m < 4; ++m) {
      float rs[4] = {0.f, 0.f, 0.f, 0.f};
#pragma unroll
      for (int n = 0; n < 4; ++n)
#pragma unroll
        for (int i = 0; i < 4; ++i) {
          float p = exp2f(s[m][n][i] * SC);
          rs[i] += p;
          int row = m * 16 + g * 4 + i, col = n * 16 + li;
          int byte = (row * 128 + col * 2) ^ ((row & 7) << 4);
          *(u16*)(Pw + byte) = f2bf(p);
        }
#pragma unroll
      for (int off = 8; off >= 1; off >>= 1)
#pragma unroll
        for (int i = 0; i < 4; ++i) rs[i] += __shfl_xor(rs[i], off);
#pragma unroll
      for (int i = 0; i < 4; ++i) l_i[m][i] += rs[i];
    }

    bf16x8 vf[4][2];
#pragma unroll
    for (int nd = 0; nd < 4; ++nd) {
      int vrow = nd * 16 + li;
      int vb0 = (vrow * 128 + g * 16) ^ ((vrow & 7) << 4);
      int vb1 = (vrow * 128 + 64 + g * 16) ^ ((vrow & 7) << 4);
      vf[nd][0] = ds_read16((lds_cp)vb + vb0);
      vf[nd][1] = ds_read16((lds_cp)vb + vb1);
    }
    bf16x8 pf[4][2];
#pragma unroll
    for (int m = 0; m < 4; ++m) {
      int prow = m * 16 + li;
      int pb0 = (prow * 128 + g * 16) ^ ((prow & 7) << 4);
      int pb1 = (prow * 128 + 64 + g * 16) ^ ((prow & 7) << 4);
      pf[m][0] = *(const bf16x8*)(Pw + pb0);
      pf[m][1] = *(const bf16x8*)(Pw + pb1);
    }
    asm volatile("s_waitcnt lgkmcnt(0)");
    __builtin_amdgcn_sched_barrier(0);
    __builtin_amdgcn_s_setprio(1);
#pragma unroll
    for (int m = 0; m < 4; ++m)
#pragma unroll
      for (int nd = 0; nd < 4; ++nd) {
        o[m][nd] = MFMA16(pf[m][0], vf[nd][0], o[m][nd]);
        o[m][nd] = MFMA16(pf[m][1], vf[nd][1], o[m][nd]);
      }
    __builtin_amdgcn_s_setprio(0);

    __builtin_amdgcn_s_barrier();
    buf ^= 1;
  }

#pragma unroll
  for (int m = 0; m < 4; ++m)
#pragma unroll
    for (int nd = 0; nd < 4; ++nd)
#pragma unroll
      for (int i = 0; i < 4; ++i) {
        size_t r = (size_t)(b * 1024 + qt * 256 + wv * 64 + m * 16 + g * 4 + i);
        Ob[r * 1024 + h * 64 + nd * 16 + li] = f2bf(o[m][nd][i] / l_i[m][i]);
      }
}

// ---------------------------------------------------------------- fused LN helpers
__device__ __forceinline__ void bsum2(float& a, float& b, float* sred, int tid) {
#pragma unroll
  for (int off = 32; off; off >>= 1) {
    a += __shfl_down(a, off);
    b += __shfl_down(b, off);
  }
  const int wv = tid >> 6;
  if ((tid & 63) == 0) { sred[wv] = a; sred[4 + wv] = b; }
  __syncthreads();
  a = sred[0] + sred[1] + sred[2] + sred[3];
  b = sred[4] + sred[5] + sred[6] + sred[7];
  __syncthreads();
}

__device__ __forceinline__ void ld4(const float* p, float v[4]) {
  float4 t = *(const float4*)p;
  v[0] = t.x; v[1] = t.y; v[2] = t.z; v[3] = t.w;
}
__device__ __forceinline__ void ld4bf(const u16* p, float v[4]) {
  union { uint2 u; u16 q[4]; } t;
  t.u = *(const uint2*)p;
#pragma unroll
  for (int j = 0; j < 4; ++j) v[j] = bf2f(t.q[j]);
}

__global__ __launch_bounds__(256) void post_attn_k(
    const float* __restrict__ x, const u16* __restrict__ G,
    const float* __restrict__ cw, const float* __restrict__ cb,
    const float* __restrict__ lag, const float* __restrict__ lab,
    const float* __restrict__ n1g, const float* __restrict__ n1b,
    u16* __restrict__ hb) {
  __shared__ float sred[8];
  const size_t row = blockIdx.x;
  const int s = (int)(row & 1023);
  const int tid = threadIdx.x, d = tid * 4;

  float xv[4], xm[4] = {0, 0, 0, 0}, xp[4] = {0, 0, 0, 0}, gv[4], cbv[4];
  ld4(&x[row * 1024 + d], xv);
  if (s > 0) ld4(&x[(row - 1) * 1024 + d], xm);
  if (s < 1023) ld4(&x[(row + 1) * 1024 + d], xp);
  ld4bf(&G[row * 1024 + d], gv);
  float c0[4], c1[4], c2[4];
  ld4(&cw[d * 3], c0);
  ld4(&cw[d * 3 + 4], c1);
  ld4(&cw[d * 3 + 8], c2);
  ld4(&cb[d], cbv);
  float w0[4] = {c0[0], c0[3], c1[2], c2[1]};
  float w1[4] = {c0[1], c1[0], c1[3], c2[2]};
  float w2[4] = {c0[2], c1[1], c2[0], c2[3]};

  float t[4], sa = 0.f, sb = 0.f;
#pragma unroll
  for (int j = 0; j < 4; ++j) {
    float loc = xm[j] * w0[j] + xv[j] * w1[j] + xp[j] * w2[j] + cbv[j];
    t[j] = xv[j] + gv[j] + 0.3f * loc;
    sa += t[j];
    sb += t[j] * t[j];
  }
  bsum2(sa, sb, sred, tid);
  float mean = sa * (1.f / 1024.f);
  float rstd = rsqrtf(sb * (1.f / 1024.f) - mean * mean + 1e-5f);
  float lg[4], lbv[4];
  ld4(&lag[d], lg);
  ld4(&lab[d], lbv);
  float hp[4];
  sa = 0.f; sb = 0.f;
#pragma unroll
  for (int j = 0; j < 4; ++j) {
    float a = (t[j] - mean) * rstd * lg[j] + lbv[j];
    hp[j] = xv[j] + a;
    sa += hp[j];
    sb += hp[j] * hp[j];
  }
  bsum2(sa, sb, sred, tid);
  float mean2 = sa * (1.f / 1024.f);
  float rstd2 = rsqrtf(sb * (1.f / 1024.f) - mean2 * mean2 + 1e-5f);
  float g2[4], b2[4];
  ld4(&n1g[d], g2);
  ld4(&n1b[d], b2);
  union { u16 q[4]; uint2 u; } pk;
#pragma unroll
  for (int j = 0; j < 4; ++j) pk.q[j] = f2bf((hp[j] - mean2) * rstd2 * g2[j] + b2[j]);
  *(uint2*)&hb[row * 1024 + d] = pk.u;
}

__global__ __launch_bounds__(256) void final_k(const u16* __restrict__ h,
                                               const u16* __restrict__ f3,
                                               const u16* __restrict__ gt,
                                               const float* __restrict__ n2g,
                                               const float* __restrict__ n2b,
                                               float* __restrict__ out) {
  __shared__ float sred[8];
  const size_t row = blockIdx.x;
  const int tid = threadIdx.x, d = tid * 4;
  float hv[4], fv[4], gv[4];
  ld4bf(&h[row * 1024 + d], hv);
  ld4bf(&f3[row * 1024 + d], fv);
  ld4bf(&gt[row * 1024 + d], gv);
  float t[4], sa = 0.f, sb = 0.f;
#pragma unroll
  for (int j = 0; j < 4; ++j) {
    t[j] = hv[j] + fv[j] * gv[j];
    sa += t[j];
    sb += t[j] * t[j];
  }
  bsum2(sa, sb, sred, tid);
  float mean = sa * (1.f / 1024.f);
  float rstd = rsqrtf(sb * (1.f / 1024.f) - mean * mean + 1e-5f);
  float g2[4], b2[4];
  ld4(&n2g[d], g2);
  ld4(&n2b[d], b2);
  float o[4];
#pragma unroll
  for (int j = 0; j < 4; ++j) o[j] = (t[j] - mean) * rstd * g2[j] + b2[j];
  *(float4*)&out[row * 1024 + d] = make_float4(o[0], o[1], o[2], o[3]);
}

// ---------------------------------------------------------------- launcher
extern "C" void kernel_launch(void* const* d_in, const int* in_sizes, int n_in,
                              void* d_out, int out_size, void* d_ws, size_t ws_size,
                              hipStream_t stream) {
  (void)in_sizes; (void)n_in; (void)out_size;
  const float* x   = (const float*)d_in[0];
  const float* Wq  = (const float*)d_in[1];
  const float* bq  = (const float*)d_in[2];
  const float* Wk  = (const float*)d_in[3];
  const float* bk  = (const float*)d_in[4];
  const float* Wv  = (const float*)d_in[5];
  const float* bv  = (const float*)d_in[6];
  const float* Wo  = (const float*)d_in[7];
  const float* bo  = (const float*)d_in[8];
  const float* cw  = (const float*)d_in[9];
  const float* cb  = (const float*)d_in[10];
  const float* lag = (const float*)d_in[11];
  const float* lab = (const float*)d_in[12];
  const float* W1  = (const float*)d_in[13];
  const float* b1  = (const float*)d_in[14];
  const float* W2  = (const float*)d_in[15];
  const float* b2  = (const float*)d_in[16];
  const float* W3  = (const float*)d_in[17];
  const float* b3  = (const float*)d_in[18];
  const float* Wg  = (const float*)d_in[19];
  const float* bg  = (const float*)d_in[20];
  const float* n1g = (const float*)d_in[21];
  const float* n1b = (const float*)d_in[22];
  const float* n2g = (const float*)d_in[23];
  const float* n2b = (const float*)d_in[24];

  const size_t MB = 1024ull * 1024ull;
  if (ws_size < 122 * MB) {
    sentinel_k<<<1, 64, 0, stream>>>((float*)d_out, (float)ws_size);
    return;
  }
  char* ws = (char*)d_ws;
  char* dob = (char*)d_out;
  u16* WoT   = (u16*)(ws + 0 * MB);
  u16* WgT   = (u16*)(ws + 2 * MB);
  u16* W1T   = (u16*)(ws + 4 * MB);
  u16* W2T   = (u16*)(ws + 12 * MB);
  u16* W3T   = (u16*)(ws + 44 * MB);
  u16* WqkvT = (u16*)(ws + 52 * MB);
  float* bqkv = (float*)(dob + 28 * MB);
  u16* xb    = (u16*)(ws + 58 * MB);
  u16* QKV   = (u16*)(ws + 74 * MB);
  u16* hb    = (u16*)(ws + 74 * MB);
  u16* f1h   = (u16*)(ws + 90 * MB);
  u16* gate  = (u16*)(ws + 90 * MB);
  u16* G     = xb;
  u16* f3    = xb;
  u16* Vt    = (u16*)dob;
  u16* globb = (u16*)(dob + 16 * MB);
  u16* f2h   = (u16*)dob;

  // ---- prep
  cast_k<<<4096, 256, 0, stream>>>(x, xb, (size_t)8192 * 1024);
  tcast5_k<<<dim3(16, 16, 5), 256, 0, stream>>>(Wq, Wk, Wv, Wo, Wg,
                                                WqkvT, WqkvT + 1024 * 1024,
                                                WqkvT + 2048 * 1024, WoT, WgT);
  tcast_k<<<dim3(16, 64), 256, 0, stream>>>(W1, W1T, 1024, 4096);
  tcast_k<<<dim3(64, 64), 256, 0, stream>>>(W2, W2T, 4096, 4096);
  tcast_k<<<dim3(64, 16), 256, 0, stream>>>(W3, W3T, 4096, 1024);
  catbias_k<<<12, 256, 0, stream>>>(bq, bk, bv, bqkv);

  // ---- attention block
  gemm8_k<4, 0, 1><<<dim3(32, 12), 512, 0, stream>>>(xb, WqkvT, bqkv, QKV, 8192, 3072, 1024, 1.0f);
  tv_k<<<dim3(128, 16), 256, 0, stream>>>(QKV + 2048, Vt, 3072);
  attn_k<<<dim3(4, 128), 256, 0, stream>>>(QKV, QKV + 1024, Vt, globb, 3072);
  gemm2_k<0, 1><<<dim3(64, 8), 256, 0, stream>>>(globb, WoT, bo, G, 8192, 1024, 1024, 1.0f);
  post_attn_k<<<8192, 256, 0, stream>>>(x, G, cw, cb, lag, lab, n1g, n1b, hb);

  // ---- FFN in 2 M-halves of 4096
  for (int hf = 0; hf < 2; ++hf) {
    const size_t M0 = (size_t)hf * 4096;
    gemm8_k<4, 1, 1><<<dim3(16, 16), 512, 0, stream>>>(hb + M0 * 1024, W1T, b1, f1h,
                                                       4096, 4096, 1024, 1.0f);
    gemm8_k<4, 1, 1><<<dim3(16, 16), 512, 0, stream>>>(f1h, W2T, b2, f2h,
                                                       4096, 4096, 4096, 1.0f);
    gemm2_k<0, 1><<<dim3(32, 8), 256, 0, stream>>>(f2h, W3T, b3, f3 + M0 * 1024,
                                                   4096, 1024, 4096, 1.0f);
  }
  gemm2_k<2, 1><<<dim3(64, 8), 256, 0, stream>>>(hb, WgT, bg, gate, 8192, 1024, 1024, 1.0f);
  final_k<<<8192, 256, 0, stream>>>(hb, f3, gate, n2g, n2b, (float*)d_out);
}

// Round 19
// 719.682 us; speedup vs baseline: 1.0447x; 1.0447x over previous
//
#include <hip/hip_runtime.h>
#include <hip/hip_bf16.h>

typedef unsigned short u16;
typedef __bf16 bf16x8 __attribute__((ext_vector_type(8)));
typedef float floatx4 __attribute__((ext_vector_type(4)));
typedef __attribute__((address_space(3))) const char* lds_cp;

#define MFMA16(a, b, c) __builtin_amdgcn_mfma_f32_16x16x32_bf16((a), (b), (c), 0, 0, 0)

__device__ __forceinline__ u16 f2bf(float f) {
  __bf16 h = (__bf16)f;
  return __builtin_bit_cast(u16, h);
}
__device__ __forceinline__ float bf2f(u16 v) {
  unsigned int u = ((unsigned int)v) << 16;
  return __builtin_bit_cast(float, u);
}

__device__ __forceinline__ void async_copy16(const void* g, void* l) {
  __builtin_amdgcn_global_load_lds(
      (const __attribute__((address_space(1))) unsigned int*)g,
      (__attribute__((address_space(3))) unsigned int*)l, 16, 0, 0);
}

// inline-asm LDS reads: opaque to the waitcnt legalizer (R11-verified +24%).
// Pair with explicit lgkmcnt(0) + sched_barrier(0) before consuming (rule #18).
__device__ __forceinline__ bf16x8 ds_read16(lds_cp p) {
  bf16x8 r;
  asm volatile("ds_read_b128 %0, %1" : "=v"(r) : "v"(p));
  return r;
}
// base + compile-time offset variant: zero per-read VALU address math (R13, +8%).
template <int IMM>
__device__ __forceinline__ bf16x8 ds_read16o(lds_cp p) {
  bf16x8 r;
  asm volatile("ds_read_b128 %0, %1 offset:%2" : "=v"(r) : "v"(p), "i"(IMM));
  return r;
}

// ---------------------------------------------------------------- sentinel
__global__ void sentinel_k(float* out, float v) {
  if (threadIdx.x == 0 && blockIdx.x == 0) out[0] = v;
}

// ---------------------------------------------------------------- cast x -> bf16
__global__ __launch_bounds__(256) void cast_k(const float* __restrict__ in,
                                              u16* __restrict__ out, size_t n) {
  size_t i = ((size_t)blockIdx.x * 256 + threadIdx.x) * 8;
  if (i >= n) return;
  float4 a = *(const float4*)&in[i];
  float4 b = *(const float4*)&in[i + 4];
  union { u16 q[8]; uint4 u; } pk;
  pk.q[0] = f2bf(a.x); pk.q[1] = f2bf(a.y); pk.q[2] = f2bf(a.z); pk.q[3] = f2bf(a.w);
  pk.q[4] = f2bf(b.x); pk.q[5] = f2bf(b.y); pk.q[6] = f2bf(b.z); pk.q[7] = f2bf(b.w);
  *(uint4*)&out[i] = pk.u;
}

// ------------------------------------------- transpose-cast W[K,N] f32 -> Wt[N,K] bf16
__device__ __forceinline__ void tcast_body(const float* __restrict__ W,
                                           u16* __restrict__ Wt, int K, int N,
                                           int bx, int by, int tid) {
  __shared__ __align__(16) u16 T[64][72];
  const int k0 = bx * 64, n0 = by * 64;
  const int r = tid >> 2, cg = (tid & 3) * 16;
#pragma unroll
  for (int j = 0; j < 4; ++j) {
    float4 w = *(const float4*)&W[(size_t)(k0 + r) * N + n0 + cg + j * 4];
    union { u16 q[4]; uint2 u; } pk;
    pk.q[0] = f2bf(w.x); pk.q[1] = f2bf(w.y); pk.q[2] = f2bf(w.z); pk.q[3] = f2bf(w.w);
    *(uint2*)&T[r][cg + j * 4] = pk.u;
  }
  __syncthreads();
  const int n = tid >> 2, kg = (tid & 3) * 16;
#pragma unroll
  for (int j = 0; j < 4; ++j) {
    union { u16 q[4]; uint2 u; } pk;
#pragma unroll
    for (int i = 0; i < 4; ++i) pk.q[i] = T[kg + j * 4 + i][n];
    *(uint2*)&Wt[(size_t)(n0 + n) * K + k0 + kg + j * 4] = pk.u;
  }
}

__global__ __launch_bounds__(256) void tcast_k(const float* __restrict__ W,
                                               u16* __restrict__ Wt, int K, int N) {
  tcast_body(W, Wt, K, N, blockIdx.x, blockIdx.y, threadIdx.x);
}

__global__ __launch_bounds__(256) void tcast5_k(
    const float* __restrict__ s0, const float* __restrict__ s1,
    const float* __restrict__ s2, const float* __restrict__ s3,
    const float* __restrict__ s4, u16* __restrict__ d0, u16* __restrict__ d1,
    u16* __restrict__ d2, u16* __restrict__ d3, u16* __restrict__ d4) {
  const float* W;
  u16* Wt;
  switch (blockIdx.z) {
    case 0: W = s0; Wt = d0; break;
    case 1: W = s1; Wt = d1; break;
    case 2: W = s2; Wt = d2; break;
    case 3: W = s3; Wt = d3; break;
    default: W = s4; Wt = d4; break;
  }
  tcast_body(W, Wt, 1024, 1024, blockIdx.x, blockIdx.y, threadIdx.x);
}

// ---------------------------------------------------------------- bias concat
__global__ __launch_bounds__(256) void catbias_k(const float* __restrict__ a,
                                                 const float* __restrict__ b,
                                                 const float* __restrict__ c,
                                                 float* __restrict__ o) {
  int i = blockIdx.x * 256 + threadIdx.x;
  if (i >= 3072) return;
  o[i] = i < 1024 ? a[i] : (i < 2048 ? b[i - 1024] : c[i - 2048]);
}

// -------------------------------- transpose V (stride VS) -> Vt[bh, dk, s] bf16
__global__ __launch_bounds__(256) void tv_k(const u16* __restrict__ V,
                                            u16* __restrict__ Vt, int VS) {
  __shared__ __align__(16) u16 T[64][72];
  const int bh = blockIdx.x, st = blockIdx.y;
  const int b = bh >> 4, h = bh & 15;
  const int s0 = st * 64;
  const int tid = threadIdx.x;
  const int r = tid >> 2, cg = (tid & 3) * 16;
#pragma unroll
  for (int j = 0; j < 2; ++j) {
    uint4 v = *(const uint4*)&V[(size_t)(b * 1024 + s0 + r) * VS + h * 64 + cg + j * 8];
    *(uint4*)&T[r][cg + j * 8] = v;
  }
  __syncthreads();
  const int dk = tid >> 2, sg = (tid & 3) * 16;
#pragma unroll
  for (int j = 0; j < 2; ++j) {
    union { u16 q[8]; uint4 u; } pk;
#pragma unroll
    for (int i = 0; i < 8; ++i) pk.q[i] = T[sg + j * 8 + i][dk];
    *(uint4*)&Vt[(size_t)(bh * 64 + dk) * 1024 + s0 + sg + j * 8] = pk.u;
  }
}

// ============================== 8-phase 256x256 GEMM (R13 schedule, verified) ====
#define LDA4(dst, P, KH, MB)                                          \
  dst[0] = ds_read16o<((MB) + 0) * 1024 + (KH) * 16384 + (P) * 32768>(aB); \
  dst[1] = ds_read16o<((MB) + 1) * 1024 + (KH) * 16384 + (P) * 32768>(aB); \
  dst[2] = ds_read16o<((MB) + 2) * 1024 + (KH) * 16384 + (P) * 32768>(aB); \
  dst[3] = ds_read16o<((MB) + 3) * 1024 + (KH) * 16384 + (P) * 32768>(aB);

#define LDB4(dst, P, KH)                                              \
  dst[0] = ds_read16o<0 * 1024 + (KH) * 16384 + (P) * 32768>(bB);     \
  dst[1] = ds_read16o<1 * 1024 + (KH) * 16384 + (P) * 32768>(bB);     \
  dst[2] = ds_read16o<2 * 1024 + (KH) * 16384 + (P) * 32768>(bB);     \
  dst[3] = ds_read16o<3 * 1024 + (KH) * 16384 + (P) * 32768>(bB);

#define FENCE_MFMA()                        \
  __builtin_amdgcn_s_barrier();             \
  asm volatile("s_waitcnt lgkmcnt(0)");     \
  __builtin_amdgcn_sched_barrier(0);

#define GEMM8_TILE(P)                                                     \
  {                                                                       \
    const int t1 = (t + 1 < NT) ? t + 1 : t + 1 - NT;                     \
    const int t2 = (t + 2 < NT) ? t + 2 : t + 2 - NT;                     \
    bf16x8 a[4], b0[4], b1[4];                                            \
    LDA4(a, P, 0, 0); LDB4(b0, P, 0);                                     \
    stA(t1, 1, (P) ^ 1);                                                  \
    FENCE_MFMA();                                                         \
    mma(a, b0, 0);                                                        \
    __builtin_amdgcn_s_barrier();                                         \
    LDA4(a, P, 1, 0); LDB4(b1, P, 1);                                     \
    stB(t2, 0, P);                                                        \
    FENCE_MFMA();                                                         \
    mma(a, b1, 0);                                                        \
    __builtin_amdgcn_s_barrier();                                         \
    LDA4(a, P, 0, 4);                                                     \
    stB(t2, 1, P);                                                        \
    FENCE_MFMA();                                                         \
    mma(a, b0, 4);                                                        \
    __builtin_amdgcn_s_barrier();                                         \
    LDA4(a, P, 1, 4);                                                     \
    stA(t2, 0, P);                                                        \
    asm volatile("s_waitcnt vmcnt(6)");                                   \
    FENCE_MFMA();                                                         \
    mma(a, b1, 4);                                                        \
    __builtin_amdgcn_s_barrier();                                         \
  }

template <int NF, int ACT, int OBF>
__global__ __launch_bounds__(512, 2) void gemm8_k(const u16* __restrict__ A,
                                                  const u16* __restrict__ Bt,
                                                  const float* __restrict__ bias,
                                                  void* __restrict__ Cout,
                                                  int M, int N, int K, float scale) {
  static_assert(NF == 4, "gemm8_k tuned for NF=4 only");
  __shared__ __align__(16) u16 As[2][2][256 * 32];
  __shared__ __align__(16) u16 Bs[2][2][256 * 32];

  const int tid = threadIdx.x;
  const int lane = tid & 63, wv = tid >> 6;
  const int wm = wv >> 2, wn = wv & 3;
  const int g = lane >> 4, li = lane & 15;
  const int m0 = blockIdx.x * 256, n0 = blockIdx.y * 256;
  const int NT = K >> 6;

  const int srow = lane >> 2;
  const int sk8 = (lane & 3) ^ ((srow >> 1) & 3);
  const size_t abase = (size_t)(m0 + wv * 32 + srow) * K + sk8 * 8;
  const size_t bbase = (size_t)(n0 + wv * 32 + srow) * K + sk8 * 8;

  auto stA = [&](int tt, int kh, int p) {
#pragma unroll
    for (int j = 0; j < 2; ++j)
      async_copy16(A + abase + (size_t)j * 16 * K + tt * 64 + kh * 32,
                   (char*)&As[p][kh][0] + (wv * 2 + j) * 1024);
  };
  auto stB = [&](int tt, int kh, int p) {
#pragma unroll
    for (int j = 0; j < 2; ++j)
      async_copy16(Bt + bbase + (size_t)j * 16 * K + tt * 64 + kh * 32,
                   (char*)&Bs[p][kh][0] + (wv * 2 + j) * 1024);
  };

  const int swz = ((li >> 1) & 3) << 4;
  lds_cp aB = (lds_cp)((const char*)&As[0][0][0] +
                       (((wm * 128 + li) * 64 + g * 16) ^ swz));
  lds_cp bB = (lds_cp)((const char*)&Bs[0][0][0] +
                       (((wn * 64 + li) * 64 + g * 16) ^ swz));

  floatx4 acc[8][4] = {};
  auto mma = [&](bf16x8 (&a)[4], bf16x8 (&b)[4], int mb) {
    __builtin_amdgcn_s_setprio(1);
#pragma unroll
    for (int mf = 0; mf < 4; ++mf)
#pragma unroll
      for (int nf = 0; nf < 4; ++nf)
        acc[mb + mf][nf] = MFMA16(a[mf], b[nf], acc[mb + mf][nf]);
    __builtin_amdgcn_s_setprio(0);
  };

  stB(0, 0, 0); stB(0, 1, 0); stA(0, 0, 0); stA(0, 1, 0);
  stB(1, 0, 1); stB(1, 1, 1); stA(1, 0, 1);
  asm volatile("s_waitcnt vmcnt(6)");
  __builtin_amdgcn_s_barrier();

  for (int tb = 0; tb < NT; tb += 2) {
    { const int t = tb;     GEMM8_TILE(0); }
    { const int t = tb + 1; GEMM8_TILE(1); }
  }
  asm volatile("s_waitcnt vmcnt(0)");

  float bv[4];
#pragma unroll
  for (int nf = 0; nf < 4; ++nf) bv[nf] = bias[n0 + wn * 64 + nf * 16 + li];
#pragma unroll
  for (int mf = 0; mf < 8; ++mf)
#pragma unroll
    for (int nf = 0; nf < 4; ++nf)
#pragma unroll
      for (int i = 0; i < 4; ++i) {
        size_t r = (size_t)m0 + wm * 128 + mf * 16 + g * 4 + i;
        size_t c = (size_t)n0 + wn * 64 + nf * 16 + li;
        float v = (acc[mf][nf][i] + bv[nf]) * scale;
        if (ACT == 1) v = 0.5f * v * (1.0f + erff(v * 0.70710678118654752f));
        if (ACT == 2) v = 1.0f / (1.0f + __expf(-v));
        if (OBF)
          ((u16*)Cout)[r * N + c] = f2bf(v);
        else
          ((float*)Cout)[r * N + c] = v;
      }
}

// ================= 128^2 GEMM, 2-phase counted pipeline (R16, verified) =======
template <int ACT, int OBF>
__global__ __launch_bounds__(256, 2) void gemm2_k(const u16* __restrict__ A,
                                                  const u16* __restrict__ Bt,
                                                  const float* __restrict__ bias,
                                                  void* __restrict__ Cout, int M,
                                                  int N, int K, float scale) {
  __shared__ __align__(16) u16 As[2][128 * 64];
  __shared__ __align__(16) u16 Bs[2][128 * 64];
  const int tid = threadIdx.x;
  const int lane = tid & 63;
  const int wv = tid >> 6;
  const int m0 = blockIdx.x * 128, n0 = blockIdx.y * 128;
  const int wm = (wv >> 1) * 64, wn = (wv & 1) * 64;
  const int NT = K >> 6;

  floatx4 acc[4][4] = {};
  const u16* Ab = A + (size_t)m0 * K;
  const u16* Bb = Bt + (size_t)n0 * K;

  int a_off[4][2], b_off[4][2];
#pragma unroll
  for (int f = 0; f < 4; ++f) {
#pragma unroll
    for (int ks = 0; ks < 2; ++ks) {
      int kk = ks * 32 + ((lane >> 4) << 3);
      int ra = wm + f * 16 + (lane & 15);
      a_off[f][ks] = (ra * 128 + kk * 2) ^ ((ra & 7) << 4);
      int rb = wn + f * 16 + (lane & 15);
      b_off[f][ks] = (rb * 128 + kk * 2) ^ ((rb & 7) << 4);
    }
  }
  const int srow = tid >> 3;
  const int scg = ((tid & 7) ^ (srow & 7)) << 3;

  auto stage = [&](int tt, int p) {
#pragma unroll
    for (int it = 0; it < 4; ++it) {
      int row = it * 32 + srow;
      async_copy16(Ab + (size_t)row * K + tt * 64 + scg,
                   (char*)&As[p][0] + (it * 256 + wv * 64) * 16);
      async_copy16(Bb + (size_t)row * K + tt * 64 + scg,
                   (char*)&Bs[p][0] + (it * 256 + wv * 64) * 16);
    }
  };

  stage(0, 0);
  stage(1, 1);
  asm volatile("s_waitcnt vmcnt(8)");
  __builtin_amdgcn_s_barrier();

  for (int t = 0; t < NT; ++t) {
    const int p = t & 1;
    const int t2 = (t + 2 < NT) ? t + 2 : t + 2 - NT;
    lds_cp aL = (lds_cp)(const char*)&As[p][0];
    lds_cp bL = (lds_cp)(const char*)&Bs[p][0];

    bf16x8 af[4][2], bfr[4][2];
#pragma unroll
    for (int f = 0; f < 4; ++f) {
      af[f][0] = ds_read16(aL + a_off[f][0]);
      af[f][1] = ds_read16(aL + a_off[f][1]);
      bfr[f][0] = ds_read16(bL + b_off[f][0]);
      bfr[f][1] = ds_read16(bL + b_off[f][1]);
    }
    asm volatile("s_waitcnt lgkmcnt(0)");
    __builtin_amdgcn_sched_barrier(0);
    __builtin_amdgcn_s_barrier();

    stage(t2, p);

    __builtin_amdgcn_s_setprio(1);
#pragma unroll
    for (int mi = 0; mi < 4; ++mi) {
#pragma unroll
      for (int ni = 0; ni < 4; ++ni) {
        acc[mi][ni] = MFMA16(af[mi][0], bfr[ni][0], acc[mi][ni]);
        acc[mi][ni] = MFMA16(af[mi][1], bfr[ni][1], acc[mi][ni]);
      }
    }
    __builtin_amdgcn_s_setprio(0);

    asm volatile("s_waitcnt vmcnt(8)");
    __builtin_amdgcn_s_barrier();
  }
  asm volatile("s_waitcnt vmcnt(0)");

  float bv[4];
#pragma unroll
  for (int ni = 0; ni < 4; ++ni) bv[ni] = bias[n0 + wn + ni * 16 + (lane & 15)];
#pragma unroll
  for (int mi = 0; mi < 4; ++mi) {
#pragma unroll
    for (int ni = 0; ni < 4; ++ni) {
#pragma unroll
      for (int i = 0; i < 4; ++i) {
        size_t r = (size_t)m0 + wm + mi * 16 + ((lane >> 4) << 2) + i;
        size_t c = (size_t)n0 + wn + ni * 16 + (lane & 15);
        float v = (acc[mi][ni][i] + bv[ni]) * scale;
        if (ACT == 1) v = 0.5f * v * (1.0f + erff(v * 0.70710678118654752f));
        if (ACT == 2) v = 1.0f / (1.0f + __expf(-v));
        if (OBF)
          ((u16*)Cout)[r * N + c] = f2bf(v);
        else
          ((float*)Cout)[r * N + c] = v;
      }
    }
  }
}

// ---------------------------------------------------------------- flash attention
// R16 config (verified ~60us): MQ=2, 32 q-rows/wave, 48KB LDS, ~21% occupancy.
// R17's MQ=4 REGRESSED (VGPR168/64KB LDS -> 11% occupancy, latency exposed).
__global__ __launch_bounds__(256) void attn_k(const u16* __restrict__ Q,
                                              const u16* __restrict__ Kb,
                                              const u16* __restrict__ Vt,
                                              u16* __restrict__ Ob, int QS) {
  __shared__ __align__(16) u16 Ks[2][64 * 64];
  __shared__ __align__(16) u16 Vs[2][64 * 64];
  __shared__ __align__(16) u16 Pl[4][2048];
  const int qt = blockIdx.x, bh = blockIdx.y;
  const int b = bh >> 4, h = bh & 15;
  const int tid = threadIdx.x;
  const int lane = tid & 63, wv = tid >> 6;
  const int g = lane >> 4, li = lane & 15;
  const float SC = 0.125f * 1.4426950408889634f;  // /sqrt(Dk) * log2(e)

  bf16x8 qf[2][2];
#pragma unroll
  for (int m = 0; m < 2; ++m) {
    int qrow = qt * 128 + wv * 32 + m * 16 + li;
    const u16* qp = Q + ((size_t)(b * 1024 + qrow)) * QS + h * 64 + g * 8;
    qf[m][0] = *(const bf16x8*)qp;
    qf[m][1] = *(const bf16x8*)(qp + 32);
  }

  float l_i[2][4] = {};
  floatx4 o[2][4] = {};

  const int r0 = tid >> 3;
  const int csrc = ((tid & 7) ^ (r0 & 7)) * 8;
  const u16* Kg = Kb + ((size_t)b * 1024) * QS + h * 64;
  const u16* Vg = Vt + ((size_t)bh * 64) * 1024;
  char* Pw = (char*)&Pl[wv][0];

  auto stage = [&](int bi, int kv0) {
#pragma unroll
    for (int it = 0; it < 2; ++it) {
      int row = it * 32 + r0;
      async_copy16(Kg + (size_t)(kv0 + row) * QS + csrc, &Ks[bi][(it * 256 + wv * 64) * 8]);
      async_copy16(Vg + (size_t)row * 1024 + kv0 + csrc, &Vs[bi][(it * 256 + wv * 64) * 8]);
    }
  };

  stage(0, 0);
  int buf = 0;

  for (int t = 0; t < 16; ++t) {
    if (t < 15) {
      stage(buf ^ 1, (t + 1) * 64);
      asm volatile("s_waitcnt vmcnt(4)");
    } else {
      asm volatile("s_waitcnt vmcnt(0)");
    }
    __builtin_amdgcn_s_barrier();

    const char* kb = (const char*)&Ks[buf][0];
    const char* vb = (const char*)&Vs[buf][0];

    bf16x8 kf[4][2];
#pragma unroll
    for (int n = 0; n < 4; ++n) {
      int krow = n * 16 + li;
      int by0 = (krow * 128 + g * 16) ^ ((krow & 7) << 4);
      int by1 = (krow * 128 + 64 + g * 16) ^ ((krow & 7) << 4);
      kf[n][0] = ds_read16((lds_cp)kb + by0);
      kf[n][1] = ds_read16((lds_cp)kb + by1);
    }
    asm volatile("s_waitcnt lgkmcnt(0)");
    __builtin_amdgcn_sched_barrier(0);
    floatx4 s[2][4];
    __builtin_amdgcn_s_setprio(1);
#pragma unroll
    for (int m = 0; m < 2; ++m)
#pragma unroll
      for (int n = 0; n < 4; ++n) {
        floatx4 z = {0.f, 0.f, 0.f, 0.f};
        s[m][n] = MFMA16(qf[m][0], kf[n][0], z);
        s[m][n] = MFMA16(qf[m][1], kf[n][1], s[m][n]);
      }
    __builtin_amdgcn_s_setprio(0);

#pragma unroll
    for (int m = 0; m < 2; ++m) {
      float rs[4] = {0.f, 0.f, 0.f, 0.f};
#pragma unroll
      for (int n = 0; n < 4; ++n)
#pragma unroll
        for (int i = 0; i < 4; ++i) {
          float p = exp2f(s[m][n][i] * SC);
          rs[i] += p;
          int row = m * 16 + g * 4 + i, col = n * 16 + li;
          int byte = (row * 128 + col * 2) ^ ((row & 7) << 4);
          *(u16*)(Pw + byte) = f2bf(p);
        }
#pragma unroll
      for (int off = 8; off >= 1; off >>= 1)
#pragma unroll
        for (int i = 0; i < 4; ++i) rs[i] += __shfl_xor(rs[i], off);
#pragma unroll
      for (int i = 0; i < 4; ++i) l_i[m][i] += rs[i];
    }

    bf16x8 vf[4][2];
#pragma unroll
    for (int nd = 0; nd < 4; ++nd) {
      int vrow = nd * 16 + li;
      int vb0 = (vrow * 128 + g * 16) ^ ((vrow & 7) << 4);
      int vb1 = (vrow * 128 + 64 + g * 16) ^ ((vrow & 7) << 4);
      vf[nd][0] = ds_read16((lds_cp)vb + vb0);
      vf[nd][1] = ds_read16((lds_cp)vb + vb1);
    }
    bf16x8 pf[2][2];
#pragma unroll
    for (int m = 0; m < 2; ++m) {
      int prow = m * 16 + li;
      int pb0 = (prow * 128 + g * 16) ^ ((prow & 7) << 4);
      int pb1 = (prow * 128 + 64 + g * 16) ^ ((prow & 7) << 4);
      pf[m][0] = *(const bf16x8*)(Pw + pb0);
      pf[m][1] = *(const bf16x8*)(Pw + pb1);
    }
    asm volatile("s_waitcnt lgkmcnt(0)");
    __builtin_amdgcn_sched_barrier(0);
    __builtin_amdgcn_s_setprio(1);
#pragma unroll
    for (int m = 0; m < 2; ++m)
#pragma unroll
      for (int nd = 0; nd < 4; ++nd) {
        o[m][nd] = MFMA16(pf[m][0], vf[nd][0], o[m][nd]);
        o[m][nd] = MFMA16(pf[m][1], vf[nd][1], o[m][nd]);
      }
    __builtin_amdgcn_s_setprio(0);

    __builtin_amdgcn_s_barrier();
    buf ^= 1;
  }

#pragma unroll
  for (int m = 0; m < 2; ++m)
#pragma unroll
    for (int nd = 0; nd < 4; ++nd)
#pragma unroll
      for (int i = 0; i < 4; ++i) {
        size_t r = (size_t)(b * 1024 + qt * 128 + wv * 32 + m * 16 + g * 4 + i);
        Ob[r * 1024 + h * 64 + nd * 16 + li] = f2bf(o[m][nd][i] / l_i[m][i]);
      }
}

// ---------------------------------------------------------------- fused LN helpers
__device__ __forceinline__ void bsum2(float& a, float& b, float* sred, int tid) {
#pragma unroll
  for (int off = 32; off; off >>= 1) {
    a += __shfl_down(a, off);
    b += __shfl_down(b, off);
  }
  const int wv = tid >> 6;
  if ((tid & 63) == 0) { sred[wv] = a; sred[4 + wv] = b; }
  __syncthreads();
  a = sred[0] + sred[1] + sred[2] + sred[3];
  b = sred[4] + sred[5] + sred[6] + sred[7];
  __syncthreads();
}

__device__ __forceinline__ void ld4(const float* p, float v[4]) {
  float4 t = *(const float4*)p;
  v[0] = t.x; v[1] = t.y; v[2] = t.z; v[3] = t.w;
}
__device__ __forceinline__ void ld4bf(const u16* p, float v[4]) {
  union { uint2 u; u16 q[4]; } t;
  t.u = *(const uint2*)p;
#pragma unroll
  for (int j = 0; j < 4; ++j) v[j] = bf2f(t.q[j]);
}

__global__ __launch_bounds__(256) void post_attn_k(
    const float* __restrict__ x, const u16* __restrict__ G,
    const float* __restrict__ cw, const float* __restrict__ cb,
    const float* __restrict__ lag, const float* __restrict__ lab,
    const float* __restrict__ n1g, const float* __restrict__ n1b,
    u16* __restrict__ hb) {
  __shared__ float sred[8];
  const size_t row = blockIdx.x;
  const int s = (int)(row & 1023);
  const int tid = threadIdx.x, d = tid * 4;

  float xv[4], xm[4] = {0, 0, 0, 0}, xp[4] = {0, 0, 0, 0}, gv[4], cbv[4];
  ld4(&x[row * 1024 + d], xv);
  if (s > 0) ld4(&x[(row - 1) * 1024 + d], xm);
  if (s < 1023) ld4(&x[(row + 1) * 1024 + d], xp);
  ld4bf(&G[row * 1024 + d], gv);
  float c0[4], c1[4], c2[4];
  ld4(&cw[d * 3], c0);
  ld4(&cw[d * 3 + 4], c1);
  ld4(&cw[d * 3 + 8], c2);
  ld4(&cb[d], cbv);
  float w0[4] = {c0[0], c0[3], c1[2], c2[1]};
  float w1[4] = {c0[1], c1[0], c1[3], c2[2]};
  float w2[4] = {c0[2], c1[1], c2[0], c2[3]};

  float t[4], sa = 0.f, sb = 0.f;
#pragma unroll
  for (int j = 0; j < 4; ++j) {
    float loc = xm[j] * w0[j] + xv[j] * w1[j] + xp[j] * w2[j] + cbv[j];
    t[j] = xv[j] + gv[j] + 0.3f * loc;
    sa += t[j];
    sb += t[j] * t[j];
  }
  bsum2(sa, sb, sred, tid);
  float mean = sa * (1.f / 1024.f);
  float rstd = rsqrtf(sb * (1.f / 1024.f) - mean * mean + 1e-5f);
  float lg[4], lbv[4];
  ld4(&lag[d], lg);
  ld4(&lab[d], lbv);
  float hp[4];
  sa = 0.f; sb = 0.f;
#pragma unroll
  for (int j = 0; j < 4; ++j) {
    float a = (t[j] - mean) * rstd * lg[j] + lbv[j];
    hp[j] = xv[j] + a;
    sa += hp[j];
    sb += hp[j] * hp[j];
  }
  bsum2(sa, sb, sred, tid);
  float mean2 = sa * (1.f / 1024.f);
  float rstd2 = rsqrtf(sb * (1.f / 1024.f) - mean2 * mean2 + 1e-5f);
  float g2[4], b2[4];
  ld4(&n1g[d], g2);
  ld4(&n1b[d], b2);
  union { u16 q[4]; uint2 u; } pk;
#pragma unroll
  for (int j = 0; j < 4; ++j) pk.q[j] = f2bf((hp[j] - mean2) * rstd2 * g2[j] + b2[j]);
  *(uint2*)&hb[row * 1024 + d] = pk.u;
}

__global__ __launch_bounds__(256) void final_k(const u16* __restrict__ h,
                                               const u16* __restrict__ f3,
                                               const u16* __restrict__ gt,
                                               const float* __restrict__ n2g,
                                               const float* __restrict__ n2b,
                                               float* __restrict__ out) {
  __shared__ float sred[8];
  const size_t row = blockIdx.x;
  const int tid = threadIdx.x, d = tid * 4;
  float hv[4], fv[4], gv[4];
  ld4bf(&h[row * 1024 + d], hv);
  ld4bf(&f3[row * 1024 + d], fv);
  ld4bf(&gt[row * 1024 + d], gv);
  float t[4], sa = 0.f, sb = 0.f;
#pragma unroll
  for (int j = 0; j < 4; ++j) {
    t[j] = hv[j] + fv[j] * gv[j];
    sa += t[j];
    sb += t[j] * t[j];
  }
  bsum2(sa, sb, sred, tid);
  float mean = sa * (1.f / 1024.f);
  float rstd = rsqrtf(sb * (1.f / 1024.f) - mean * mean + 1e-5f);
  float g2[4], b2[4];
  ld4(&n2g[d], g2);
  ld4(&n2b[d], b2);
  float o[4];
#pragma unroll
  for (int j = 0; j < 4; ++j) o[j] = (t[j] - mean) * rstd * g2[j] + b2[j];
  *(float4*)&out[row * 1024 + d] = make_float4(o[0], o[1], o[2], o[3]);
}

// ---------------------------------------------------------------- launcher
extern "C" void kernel_launch(void* const* d_in, const int* in_sizes, int n_in,
                              void* d_out, int out_size, void* d_ws, size_t ws_size,
                              hipStream_t stream) {
  (void)in_sizes; (void)n_in; (void)out_size;
  const float* x   = (const float*)d_in[0];
  const float* Wq  = (const float*)d_in[1];
  const float* bq  = (const float*)d_in[2];
  const float* Wk  = (const float*)d_in[3];
  const float* bk  = (const float*)d_in[4];
  const float* Wv  = (const float*)d_in[5];
  const float* bv  = (const float*)d_in[6];
  const float* Wo  = (const float*)d_in[7];
  const float* bo  = (const float*)d_in[8];
  const float* cw  = (const float*)d_in[9];
  const float* cb  = (const float*)d_in[10];
  const float* lag = (const float*)d_in[11];
  const float* lab = (const float*)d_in[12];
  const float* W1  = (const float*)d_in[13];
  const float* b1  = (const float*)d_in[14];
  const float* W2  = (const float*)d_in[15];
  const float* b2  = (const float*)d_in[16];
  const float* W3  = (const float*)d_in[17];
  const float* b3  = (const float*)d_in[18];
  const float* Wg  = (const float*)d_in[19];
  const float* bg  = (const float*)d_in[20];
  const float* n1g = (const float*)d_in[21];
  const float* n1b = (const float*)d_in[22];
  const float* n2g = (const float*)d_in[23];
  const float* n2b = (const float*)d_in[24];

  const size_t MB = 1024ull * 1024ull;
  if (ws_size < 122 * MB) {
    sentinel_k<<<1, 64, 0, stream>>>((float*)d_out, (float)ws_size);
    return;
  }
  char* ws = (char*)d_ws;
  char* dob = (char*)d_out;
  u16* WoT   = (u16*)(ws + 0 * MB);
  u16* WgT   = (u16*)(ws + 2 * MB);
  u16* W1T   = (u16*)(ws + 4 * MB);
  u16* W2T   = (u16*)(ws + 12 * MB);
  u16* W3T   = (u16*)(ws + 44 * MB);
  u16* WqkvT = (u16*)(ws + 52 * MB);
  float* bqkv = (float*)(dob + 28 * MB);
  u16* xb    = (u16*)(ws + 58 * MB);
  u16* QKV   = (u16*)(ws + 74 * MB);
  u16* hb    = (u16*)(ws + 74 * MB);
  u16* f1h   = (u16*)(ws + 90 * MB);
  u16* gate  = (u16*)(ws + 90 * MB);
  u16* G     = xb;
  u16* f3    = xb;
  u16* Vt    = (u16*)dob;
  u16* globb = (u16*)(dob + 16 * MB);
  u16* f2h   = (u16*)dob;

  // ---- prep
  cast_k<<<4096, 256, 0, stream>>>(x, xb, (size_t)8192 * 1024);
  tcast5_k<<<dim3(16, 16, 5), 256, 0, stream>>>(Wq, Wk, Wv, Wo, Wg,
                                                WqkvT, WqkvT + 1024 * 1024,
                                                WqkvT + 2048 * 1024, WoT, WgT);
  tcast_k<<<dim3(16, 64), 256, 0, stream>>>(W1, W1T, 1024, 4096);
  tcast_k<<<dim3(64, 64), 256, 0, stream>>>(W2, W2T, 4096, 4096);
  tcast_k<<<dim3(64, 16), 256, 0, stream>>>(W3, W3T, 4096, 1024);
  catbias_k<<<12, 256, 0, stream>>>(bq, bk, bv, bqkv);

  // ---- attention block
  gemm8_k<4, 0, 1><<<dim3(32, 12), 512, 0, stream>>>(xb, WqkvT, bqkv, QKV, 8192, 3072, 1024, 1.0f);
  tv_k<<<dim3(128, 16), 256, 0, stream>>>(QKV + 2048, Vt, 3072);
  attn_k<<<dim3(8, 128), 256, 0, stream>>>(QKV, QKV + 1024, Vt, globb, 3072);
  gemm2_k<0, 1><<<dim3(64, 8), 256, 0, stream>>>(globb, WoT, bo, G, 8192, 1024, 1024, 1.0f);
  post_attn_k<<<8192, 256, 0, stream>>>(x, G, cw, cb, lag, lab, n1g, n1b, hb);

  // ---- FFN in 2 M-halves of 4096
  for (int hf = 0; hf < 2; ++hf) {
    const size_t M0 = (size_t)hf * 4096;
    gemm8_k<4, 1, 1><<<dim3(16, 16), 512, 0, stream>>>(hb + M0 * 1024, W1T, b1, f1h,
                                                       4096, 4096, 1024, 1.0f);
    gemm8_k<4, 1, 1><<<dim3(16, 16), 512, 0, stream>>>(f1h, W2T, b2, f2h,
                                                       4096, 4096, 4096, 1.0f);
    gemm2_k<0, 1><<<dim3(32, 8), 256, 0, stream>>>(f2h, W3T, b3, f3 + M0 * 1024,
                                                   4096, 1024, 4096, 1.0f);
  }
  gemm2_k<2, 1><<<dim3(64, 8), 256, 0, stream>>>(hb, WgT, bg, gate, 8192, 1024, 1024, 1.0f);
  final_k<<<8192, 256, 0, stream>>>(hb, f3, gate, n2g, n2b, (float*)d_out);
}

// Round 20
// 707.314 us; speedup vs baseline: 1.0629x; 1.0175x over previous
//
#include <hip/hip_runtime.h>
#include <hip/hip_bf16.h>

typedef unsigned short u16;
typedef __bf16 bf16x8 __attribute__((ext_vector_type(8)));
typedef float floatx4 __attribute__((ext_vector_type(4)));
typedef __attribute__((address_space(3))) const char* lds_cp;

#define MFMA16(a, b, c) __builtin_amdgcn_mfma_f32_16x16x32_bf16((a), (b), (c), 0, 0, 0)

__device__ __forceinline__ u16 f2bf(float f) {
  __bf16 h = (__bf16)f;
  return __builtin_bit_cast(u16, h);
}
__device__ __forceinline__ float bf2f(u16 v) {
  unsigned int u = ((unsigned int)v) << 16;
  return __builtin_bit_cast(float, u);
}

__device__ __forceinline__ void async_copy16(const void* g, void* l) {
  __builtin_amdgcn_global_load_lds(
      (const __attribute__((address_space(1))) unsigned int*)g,
      (__attribute__((address_space(3))) unsigned int*)l, 16, 0, 0);
}

// inline-asm LDS reads: opaque to the waitcnt legalizer (R11-verified +24%).
// Pair with explicit lgkmcnt(0) + sched_barrier(0) before consuming (rule #18).
__device__ __forceinline__ bf16x8 ds_read16(lds_cp p) {
  bf16x8 r;
  asm volatile("ds_read_b128 %0, %1" : "=v"(r) : "v"(p));
  return r;
}
// base + compile-time offset variant: zero per-read VALU address math (R13, +8%).
template <int IMM>
__device__ __forceinline__ bf16x8 ds_read16o(lds_cp p) {
  bf16x8 r;
  asm volatile("ds_read_b128 %0, %1 offset:%2" : "=v"(r) : "v"(p), "i"(IMM));
  return r;
}

// ---------------------------------------------------------------- sentinel
__global__ void sentinel_k(float* out, float v) {
  if (threadIdx.x == 0 && blockIdx.x == 0) out[0] = v;
}

// ---------------------------------------------------------------- cast x -> bf16
__global__ __launch_bounds__(256) void cast_k(const float* __restrict__ in,
                                              u16* __restrict__ out, size_t n) {
  size_t i = ((size_t)blockIdx.x * 256 + threadIdx.x) * 8;
  if (i >= n) return;
  float4 a = *(const float4*)&in[i];
  float4 b = *(const float4*)&in[i + 4];
  union { u16 q[8]; uint4 u; } pk;
  pk.q[0] = f2bf(a.x); pk.q[1] = f2bf(a.y); pk.q[2] = f2bf(a.z); pk.q[3] = f2bf(a.w);
  pk.q[4] = f2bf(b.x); pk.q[5] = f2bf(b.y); pk.q[6] = f2bf(b.z); pk.q[7] = f2bf(b.w);
  *(uint4*)&out[i] = pk.u;
}

// ------------------------------------------- transpose-cast W[K,N] f32 -> Wt[N,K] bf16
__device__ __forceinline__ void tcast_body(const float* __restrict__ W,
                                           u16* __restrict__ Wt, int K, int N,
                                           int bx, int by, int tid) {
  __shared__ __align__(16) u16 T[64][72];
  const int k0 = bx * 64, n0 = by * 64;
  const int r = tid >> 2, cg = (tid & 3) * 16;
#pragma unroll
  for (int j = 0; j < 4; ++j) {
    float4 w = *(const float4*)&W[(size_t)(k0 + r) * N + n0 + cg + j * 4];
    union { u16 q[4]; uint2 u; } pk;
    pk.q[0] = f2bf(w.x); pk.q[1] = f2bf(w.y); pk.q[2] = f2bf(w.z); pk.q[3] = f2bf(w.w);
    *(uint2*)&T[r][cg + j * 4] = pk.u;
  }
  __syncthreads();
  const int n = tid >> 2, kg = (tid & 3) * 16;
#pragma unroll
  for (int j = 0; j < 4; ++j) {
    union { u16 q[4]; uint2 u; } pk;
#pragma unroll
    for (int i = 0; i < 4; ++i) pk.q[i] = T[kg + j * 4 + i][n];
    *(uint2*)&Wt[(size_t)(n0 + n) * K + k0 + kg + j * 4] = pk.u;
  }
}

__global__ __launch_bounds__(256) void tcast_k(const float* __restrict__ W,
                                               u16* __restrict__ Wt, int K, int N) {
  tcast_body(W, Wt, K, N, blockIdx.x, blockIdx.y, threadIdx.x);
}

__global__ __launch_bounds__(256) void tcast5_k(
    const float* __restrict__ s0, const float* __restrict__ s1,
    const float* __restrict__ s2, const float* __restrict__ s3,
    const float* __restrict__ s4, u16* __restrict__ d0, u16* __restrict__ d1,
    u16* __restrict__ d2, u16* __restrict__ d3, u16* __restrict__ d4) {
  const float* W;
  u16* Wt;
  switch (blockIdx.z) {
    case 0: W = s0; Wt = d0; break;
    case 1: W = s1; Wt = d1; break;
    case 2: W = s2; Wt = d2; break;
    case 3: W = s3; Wt = d3; break;
    default: W = s4; Wt = d4; break;
  }
  tcast_body(W, Wt, 1024, 1024, blockIdx.x, blockIdx.y, threadIdx.x);
}

// ---------------------------------------------------------------- bias concat
__global__ __launch_bounds__(256) void catbias_k(const float* __restrict__ a,
                                                 const float* __restrict__ b,
                                                 const float* __restrict__ c,
                                                 float* __restrict__ o) {
  int i = blockIdx.x * 256 + threadIdx.x;
  if (i >= 3072) return;
  o[i] = i < 1024 ? a[i] : (i < 2048 ? b[i - 1024] : c[i - 2048]);
}

// -------------------------------- transpose V (stride VS) -> Vt[bh, dk, s] bf16
__global__ __launch_bounds__(256) void tv_k(const u16* __restrict__ V,
                                            u16* __restrict__ Vt, int VS) {
  __shared__ __align__(16) u16 T[64][72];
  const int bh = blockIdx.x, st = blockIdx.y;
  const int b = bh >> 4, h = bh & 15;
  const int s0 = st * 64;
  const int tid = threadIdx.x;
  const int r = tid >> 2, cg = (tid & 3) * 16;
#pragma unroll
  for (int j = 0; j < 2; ++j) {
    uint4 v = *(const uint4*)&V[(size_t)(b * 1024 + s0 + r) * VS + h * 64 + cg + j * 8];
    *(uint4*)&T[r][cg + j * 8] = v;
  }
  __syncthreads();
  const int dk = tid >> 2, sg = (tid & 3) * 16;
#pragma unroll
  for (int j = 0; j < 2; ++j) {
    union { u16 q[8]; uint4 u; } pk;
#pragma unroll
    for (int i = 0; i < 8; ++i) pk.q[i] = T[sg + j * 8 + i][dk];
    *(uint4*)&Vt[(size_t)(bh * 64 + dk) * 1024 + s0 + sg + j * 8] = pk.u;
  }
}

// ============================== 8-phase 256x256 GEMM (R13 schedule, verified) ====
#define LDA4(dst, P, KH, MB)                                          \
  dst[0] = ds_read16o<((MB) + 0) * 1024 + (KH) * 16384 + (P) * 32768>(aB); \
  dst[1] = ds_read16o<((MB) + 1) * 1024 + (KH) * 16384 + (P) * 32768>(aB); \
  dst[2] = ds_read16o<((MB) + 2) * 1024 + (KH) * 16384 + (P) * 32768>(aB); \
  dst[3] = ds_read16o<((MB) + 3) * 1024 + (KH) * 16384 + (P) * 32768>(aB);

#define LDB4(dst, P, KH)                                              \
  dst[0] = ds_read16o<0 * 1024 + (KH) * 16384 + (P) * 32768>(bB);     \
  dst[1] = ds_read16o<1 * 1024 + (KH) * 16384 + (P) * 32768>(bB);     \
  dst[2] = ds_read16o<2 * 1024 + (KH) * 16384 + (P) * 32768>(bB);     \
  dst[3] = ds_read16o<3 * 1024 + (KH) * 16384 + (P) * 32768>(bB);

#define FENCE_MFMA()                        \
  __builtin_amdgcn_s_barrier();             \
  asm volatile("s_waitcnt lgkmcnt(0)");     \
  __builtin_amdgcn_sched_barrier(0);

#define GEMM8_TILE(P)                                                     \
  {                                                                       \
    const int t1 = (t + 1 < NT) ? t + 1 : t + 1 - NT;                     \
    const int t2 = (t + 2 < NT) ? t + 2 : t + 2 - NT;                     \
    bf16x8 a[4], b0[4], b1[4];                                            \
    LDA4(a, P, 0, 0); LDB4(b0, P, 0);                                     \
    stA(t1, 1, (P) ^ 1);                                                  \
    FENCE_MFMA();                                                         \
    mma(a, b0, 0);                                                        \
    __builtin_amdgcn_s_barrier();                                         \
    LDA4(a, P, 1, 0); LDB4(b1, P, 1);                                     \
    stB(t2, 0, P);                                                        \
    FENCE_MFMA();                                                         \
    mma(a, b1, 0);                                                        \
    __builtin_amdgcn_s_barrier();                                         \
    LDA4(a, P, 0, 4);                                                     \
    stB(t2, 1, P);                                                        \
    FENCE_MFMA();                                                         \
    mma(a, b0, 4);                                                        \
    __builtin_amdgcn_s_barrier();                                         \
    LDA4(a, P, 1, 4);                                                     \
    stA(t2, 0, P);                                                        \
    asm volatile("s_waitcnt vmcnt(6)");                                   \
    FENCE_MFMA();                                                         \
    mma(a, b1, 4);                                                        \
    __builtin_amdgcn_s_barrier();                                         \
  }

template <int NF, int ACT, int OBF>
__global__ __launch_bounds__(512, 2) void gemm8_k(const u16* __restrict__ A,
                                                  const u16* __restrict__ Bt,
                                                  const float* __restrict__ bias,
                                                  void* __restrict__ Cout,
                                                  int M, int N, int K, float scale) {
  static_assert(NF == 4, "gemm8_k tuned for NF=4 only");
  __shared__ __align__(16) u16 As[2][2][256 * 32];
  __shared__ __align__(16) u16 Bs[2][2][256 * 32];

  const int tid = threadIdx.x;
  const int lane = tid & 63, wv = tid >> 6;
  const int wm = wv >> 2, wn = wv & 3;
  const int g = lane >> 4, li = lane & 15;
  const int m0 = blockIdx.x * 256, n0 = blockIdx.y * 256;
  const int NT = K >> 6;

  const int srow = lane >> 2;
  const int sk8 = (lane & 3) ^ ((srow >> 1) & 3);
  const size_t abase = (size_t)(m0 + wv * 32 + srow) * K + sk8 * 8;
  const size_t bbase = (size_t)(n0 + wv * 32 + srow) * K + sk8 * 8;

  auto stA = [&](int tt, int kh, int p) {
#pragma unroll
    for (int j = 0; j < 2; ++j)
      async_copy16(A + abase + (size_t)j * 16 * K + tt * 64 + kh * 32,
                   (char*)&As[p][kh][0] + (wv * 2 + j) * 1024);
  };
  auto stB = [&](int tt, int kh, int p) {
#pragma unroll
    for (int j = 0; j < 2; ++j)
      async_copy16(Bt + bbase + (size_t)j * 16 * K + tt * 64 + kh * 32,
                   (char*)&Bs[p][kh][0] + (wv * 2 + j) * 1024);
  };

  const int swz = ((li >> 1) & 3) << 4;
  lds_cp aB = (lds_cp)((const char*)&As[0][0][0] +
                       (((wm * 128 + li) * 64 + g * 16) ^ swz));
  lds_cp bB = (lds_cp)((const char*)&Bs[0][0][0] +
                       (((wn * 64 + li) * 64 + g * 16) ^ swz));

  floatx4 acc[8][4] = {};
  auto mma = [&](bf16x8 (&a)[4], bf16x8 (&b)[4], int mb) {
    __builtin_amdgcn_s_setprio(1);
#pragma unroll
    for (int mf = 0; mf < 4; ++mf)
#pragma unroll
      for (int nf = 0; nf < 4; ++nf)
        acc[mb + mf][nf] = MFMA16(a[mf], b[nf], acc[mb + mf][nf]);
    __builtin_amdgcn_s_setprio(0);
  };

  stB(0, 0, 0); stB(0, 1, 0); stA(0, 0, 0); stA(0, 1, 0);
  stB(1, 0, 1); stB(1, 1, 1); stA(1, 0, 1);
  asm volatile("s_waitcnt vmcnt(6)");
  __builtin_amdgcn_s_barrier();

  for (int tb = 0; tb < NT; tb += 2) {
    { const int t = tb;     GEMM8_TILE(0); }
    { const int t = tb + 1; GEMM8_TILE(1); }
  }
  asm volatile("s_waitcnt vmcnt(0)");

  float bv[4];
#pragma unroll
  for (int nf = 0; nf < 4; ++nf) bv[nf] = bias[n0 + wn * 64 + nf * 16 + li];
#pragma unroll
  for (int mf = 0; mf < 8; ++mf)
#pragma unroll
    for (int nf = 0; nf < 4; ++nf)
#pragma unroll
      for (int i = 0; i < 4; ++i) {
        size_t r = (size_t)m0 + wm * 128 + mf * 16 + g * 4 + i;
        size_t c = (size_t)n0 + wn * 64 + nf * 16 + li;
        float v = (acc[mf][nf][i] + bv[nf]) * scale;
        if (ACT == 1) v = 0.5f * v * (1.0f + erff(v * 0.70710678118654752f));
        if (ACT == 2) v = 1.0f / (1.0f + __expf(-v));
        if (OBF)
          ((u16*)Cout)[r * N + c] = f2bf(v);
        else
          ((float*)Cout)[r * N + c] = v;
      }
}

// ================= 128^2 GEMM, 2-phase counted pipeline (R16, verified) =======
template <int ACT, int OBF>
__global__ __launch_bounds__(256, 2) void gemm2_k(const u16* __restrict__ A,
                                                  const u16* __restrict__ Bt,
                                                  const float* __restrict__ bias,
                                                  void* __restrict__ Cout, int M,
                                                  int N, int K, float scale) {
  __shared__ __align__(16) u16 As[2][128 * 64];
  __shared__ __align__(16) u16 Bs[2][128 * 64];
  const int tid = threadIdx.x;
  const int lane = tid & 63;
  const int wv = tid >> 6;
  const int m0 = blockIdx.x * 128, n0 = blockIdx.y * 128;
  const int wm = (wv >> 1) * 64, wn = (wv & 1) * 64;
  const int NT = K >> 6;

  floatx4 acc[4][4] = {};
  const u16* Ab = A + (size_t)m0 * K;
  const u16* Bb = Bt + (size_t)n0 * K;

  int a_off[4][2], b_off[4][2];
#pragma unroll
  for (int f = 0; f < 4; ++f) {
#pragma unroll
    for (int ks = 0; ks < 2; ++ks) {
      int kk = ks * 32 + ((lane >> 4) << 3);
      int ra = wm + f * 16 + (lane & 15);
      a_off[f][ks] = (ra * 128 + kk * 2) ^ ((ra & 7) << 4);
      int rb = wn + f * 16 + (lane & 15);
      b_off[f][ks] = (rb * 128 + kk * 2) ^ ((rb & 7) << 4);
    }
  }
  const int srow = tid >> 3;
  const int scg = ((tid & 7) ^ (srow & 7)) << 3;

  auto stage = [&](int tt, int p) {
#pragma unroll
    for (int it = 0; it < 4; ++it) {
      int row = it * 32 + srow;
      async_copy16(Ab + (size_t)row * K + tt * 64 + scg,
                   (char*)&As[p][0] + (it * 256 + wv * 64) * 16);
      async_copy16(Bb + (size_t)row * K + tt * 64 + scg,
                   (char*)&Bs[p][0] + (it * 256 + wv * 64) * 16);
    }
  };

  stage(0, 0);
  stage(1, 1);
  asm volatile("s_waitcnt vmcnt(8)");
  __builtin_amdgcn_s_barrier();

  for (int t = 0; t < NT; ++t) {
    const int p = t & 1;
    const int t2 = (t + 2 < NT) ? t + 2 : t + 2 - NT;
    lds_cp aL = (lds_cp)(const char*)&As[p][0];
    lds_cp bL = (lds_cp)(const char*)&Bs[p][0];

    bf16x8 af[4][2], bfr[4][2];
#pragma unroll
    for (int f = 0; f < 4; ++f) {
      af[f][0] = ds_read16(aL + a_off[f][0]);
      af[f][1] = ds_read16(aL + a_off[f][1]);
      bfr[f][0] = ds_read16(bL + b_off[f][0]);
      bfr[f][1] = ds_read16(bL + b_off[f][1]);
    }
    asm volatile("s_waitcnt lgkmcnt(0)");
    __builtin_amdgcn_sched_barrier(0);
    __builtin_amdgcn_s_barrier();

    stage(t2, p);

    __builtin_amdgcn_s_setprio(1);
#pragma unroll
    for (int mi = 0; mi < 4; ++mi) {
#pragma unroll
      for (int ni = 0; ni < 4; ++ni) {
        acc[mi][ni] = MFMA16(af[mi][0], bfr[ni][0], acc[mi][ni]);
        acc[mi][ni] = MFMA16(af[mi][1], bfr[ni][1], acc[mi][ni]);
      }
    }
    __builtin_amdgcn_s_setprio(0);

    asm volatile("s_waitcnt vmcnt(8)");
    __builtin_amdgcn_s_barrier();
  }
  asm volatile("s_waitcnt vmcnt(0)");

  float bv[4];
#pragma unroll
  for (int ni = 0; ni < 4; ++ni) bv[ni] = bias[n0 + wn + ni * 16 + (lane & 15)];
#pragma unroll
  for (int mi = 0; mi < 4; ++mi) {
#pragma unroll
    for (int ni = 0; ni < 4; ++ni) {
#pragma unroll
      for (int i = 0; i < 4; ++i) {
        size_t r = (size_t)m0 + wm + mi * 16 + ((lane >> 4) << 2) + i;
        size_t c = (size_t)n0 + wn + ni * 16 + (lane & 15);
        float v = (acc[mi][ni][i] + bv[ni]) * scale;
        if (ACT == 1) v = 0.5f * v * (1.0f + erff(v * 0.70710678118654752f));
        if (ACT == 2) v = 1.0f / (1.0f + __expf(-v));
        if (OBF)
          ((u16*)Cout)[r * N + c] = f2bf(v);
        else
          ((float*)Cout)[r * N + c] = v;
      }
    }
  }
}

// ---------------------------------------------------------------- flash attention
// R16 config (verified ~60us): MQ=2, 32 q-rows/wave, 48KB LDS, ~21% occupancy.
__global__ __launch_bounds__(256) void attn_k(const u16* __restrict__ Q,
                                              const u16* __restrict__ Kb,
                                              const u16* __restrict__ Vt,
                                              u16* __restrict__ Ob, int QS) {
  __shared__ __align__(16) u16 Ks[2][64 * 64];
  __shared__ __align__(16) u16 Vs[2][64 * 64];
  __shared__ __align__(16) u16 Pl[4][2048];
  const int qt = blockIdx.x, bh = blockIdx.y;
  const int b = bh >> 4, h = bh & 15;
  const int tid = threadIdx.x;
  const int lane = tid & 63, wv = tid >> 6;
  const int g = lane >> 4, li = lane & 15;
  const float SC = 0.125f * 1.4426950408889634f;  // /sqrt(Dk) * log2(e)

  bf16x8 qf[2][2];
#pragma unroll
  for (int m = 0; m < 2; ++m) {
    int qrow = qt * 128 + wv * 32 + m * 16 + li;
    const u16* qp = Q + ((size_t)(b * 1024 + qrow)) * QS + h * 64 + g * 8;
    qf[m][0] = *(const bf16x8*)qp;
    qf[m][1] = *(const bf16x8*)(qp + 32);
  }

  float l_i[2][4] = {};
  floatx4 o[2][4] = {};

  const int r0 = tid >> 3;
  const int csrc = ((tid & 7) ^ (r0 & 7)) * 8;
  const u16* Kg = Kb + ((size_t)b * 1024) * QS + h * 64;
  const u16* Vg = Vt + ((size_t)bh * 64) * 1024;
  char* Pw = (char*)&Pl[wv][0];

  auto stage = [&](int bi, int kv0) {
#pragma unroll
    for (int it = 0; it < 2; ++it) {
      int row = it * 32 + r0;
      async_copy16(Kg + (size_t)(kv0 + row) * QS + csrc, &Ks[bi][(it * 256 + wv * 64) * 8]);
      async_copy16(Vg + (size_t)row * 1024 + kv0 + csrc, &Vs[bi][(it * 256 + wv * 64) * 8]);
    }
  };

  stage(0, 0);
  int buf = 0;

  for (int t = 0; t < 16; ++t) {
    if (t < 15) {
      stage(buf ^ 1, (t + 1) * 64);
      asm volatile("s_waitcnt vmcnt(4)");
    } else {
      asm volatile("s_waitcnt vmcnt(0)");
    }
    __builtin_amdgcn_s_barrier();

    const char* kb = (const char*)&Ks[buf][0];
    const char* vb = (const char*)&Vs[buf][0];

    bf16x8 kf[4][2];
#pragma unroll
    for (int n = 0; n < 4; ++n) {
      int krow = n * 16 + li;
      int by0 = (krow * 128 + g * 16) ^ ((krow & 7) << 4);
      int by1 = (krow * 128 + 64 + g * 16) ^ ((krow & 7) << 4);
      kf[n][0] = ds_read16((lds_cp)kb + by0);
      kf[n][1] = ds_read16((lds_cp)kb + by1);
    }
    asm volatile("s_waitcnt lgkmcnt(0)");
    __builtin_amdgcn_sched_barrier(0);
    floatx4 s[2][4];
    __builtin_amdgcn_s_setprio(1);
#pragma unroll
    for (int m = 0; m < 2; ++m)
#pragma unroll
      for (int n = 0; n < 4; ++n) {
        floatx4 z = {0.f, 0.f, 0.f, 0.f};
        s[m][n] = MFMA16(qf[m][0], kf[n][0], z);
        s[m][n] = MFMA16(qf[m][1], kf[n][1], s[m][n]);
      }
    __builtin_amdgcn_s_setprio(0);

#pragma unroll
    for (int m = 0; m < 2; ++m) {
      float rs[4] = {0.f, 0.f, 0.f, 0.f};
#pragma unroll
      for (int n = 0; n < 4; ++n)
#pragma unroll
        for (int i = 0; i < 4; ++i) {
          float p = exp2f(s[m][n][i] * SC);
          rs[i] += p;
          int row = m * 16 + g * 4 + i, col = n * 16 + li;
          int byte = (row * 128 + col * 2) ^ ((row & 7) << 4);
          *(u16*)(Pw + byte) = f2bf(p);
        }
#pragma unroll
      for (int off = 8; off >= 1; off >>= 1)
#pragma unroll
        for (int i = 0; i < 4; ++i) rs[i] += __shfl_xor(rs[i], off);
#pragma unroll
      for (int i = 0; i < 4; ++i) l_i[m][i] += rs[i];
    }

    bf16x8 vf[4][2];
#pragma unroll
    for (int nd = 0; nd < 4; ++nd) {
      int vrow = nd * 16 + li;
      int vb0 = (vrow * 128 + g * 16) ^ ((vrow & 7) << 4);
      int vb1 = (vrow * 128 + 64 + g * 16) ^ ((vrow & 7) << 4);
      vf[nd][0] = ds_read16((lds_cp)vb + vb0);
      vf[nd][1] = ds_read16((lds_cp)vb + vb1);
    }
    bf16x8 pf[2][2];
#pragma unroll
    for (int m = 0; m < 2; ++m) {
      int prow = m * 16 + li;
      int pb0 = (prow * 128 + g * 16) ^ ((prow & 7) << 4);
      int pb1 = (prow * 128 + 64 + g * 16) ^ ((prow & 7) << 4);
      pf[m][0] = *(const bf16x8*)(Pw + pb0);
      pf[m][1] = *(const bf16x8*)(Pw + pb1);
    }
    asm volatile("s_waitcnt lgkmcnt(0)");
    __builtin_amdgcn_sched_barrier(0);
    __builtin_amdgcn_s_setprio(1);
#pragma unroll
    for (int m = 0; m < 2; ++m)
#pragma unroll
      for (int nd = 0; nd < 4; ++nd) {
        o[m][nd] = MFMA16(pf[m][0], vf[nd][0], o[m][nd]);
        o[m][nd] = MFMA16(pf[m][1], vf[nd][1], o[m][nd]);
      }
    __builtin_amdgcn_s_setprio(0);

    __builtin_amdgcn_s_barrier();
    buf ^= 1;
  }

#pragma unroll
  for (int m = 0; m < 2; ++m)
#pragma unroll
    for (int nd = 0; nd < 4; ++nd)
#pragma unroll
      for (int i = 0; i < 4; ++i) {
        size_t r = (size_t)(b * 1024 + qt * 128 + wv * 32 + m * 16 + g * 4 + i);
        Ob[r * 1024 + h * 64 + nd * 16 + li] = f2bf(o[m][nd][i] / l_i[m][i]);
      }
}

// ---------------------------------------------------------------- fused LN helpers
__device__ __forceinline__ void bsum2(float& a, float& b, float* sred, int tid) {
#pragma unroll
  for (int off = 32; off; off >>= 1) {
    a += __shfl_down(a, off);
    b += __shfl_down(b, off);
  }
  const int wv = tid >> 6;
  if ((tid & 63) == 0) { sred[wv] = a; sred[4 + wv] = b; }
  __syncthreads();
  a = sred[0] + sred[1] + sred[2] + sred[3];
  b = sred[4] + sred[5] + sred[6] + sred[7];
  __syncthreads();
}

__device__ __forceinline__ void ld4(const float* p, float v[4]) {
  float4 t = *(const float4*)p;
  v[0] = t.x; v[1] = t.y; v[2] = t.z; v[3] = t.w;
}
__device__ __forceinline__ void ld4bf(const u16* p, float v[4]) {
  union { uint2 u; u16 q[4]; } t;
  t.u = *(const uint2*)p;
#pragma unroll
  for (int j = 0; j < 4; ++j) v[j] = bf2f(t.q[j]);
}

__global__ __launch_bounds__(256) void post_attn_k(
    const float* __restrict__ x, const u16* __restrict__ G,
    const float* __restrict__ cw, const float* __restrict__ cb,
    const float* __restrict__ lag, const float* __restrict__ lab,
    const float* __restrict__ n1g, const float* __restrict__ n1b,
    u16* __restrict__ hb) {
  __shared__ float sred[8];
  const size_t row = blockIdx.x;
  const int s = (int)(row & 1023);
  const int tid = threadIdx.x, d = tid * 4;

  float xv[4], xm[4] = {0, 0, 0, 0}, xp[4] = {0, 0, 0, 0}, gv[4], cbv[4];
  ld4(&x[row * 1024 + d], xv);
  if (s > 0) ld4(&x[(row - 1) * 1024 + d], xm);
  if (s < 1023) ld4(&x[(row + 1) * 1024 + d], xp);
  ld4bf(&G[row * 1024 + d], gv);
  float c0[4], c1[4], c2[4];
  ld4(&cw[d * 3], c0);
  ld4(&cw[d * 3 + 4], c1);
  ld4(&cw[d * 3 + 8], c2);
  ld4(&cb[d], cbv);
  float w0[4] = {c0[0], c0[3], c1[2], c2[1]};
  float w1[4] = {c0[1], c1[0], c1[3], c2[2]};
  float w2[4] = {c0[2], c1[1], c2[0], c2[3]};

  float t[4], sa = 0.f, sb = 0.f;
#pragma unroll
  for (int j = 0; j < 4; ++j) {
    float loc = xm[j] * w0[j] + xv[j] * w1[j] + xp[j] * w2[j] + cbv[j];
    t[j] = xv[j] + gv[j] + 0.3f * loc;
    sa += t[j];
    sb += t[j] * t[j];
  }
  bsum2(sa, sb, sred, tid);
  float mean = sa * (1.f / 1024.f);
  float rstd = rsqrtf(sb * (1.f / 1024.f) - mean * mean + 1e-5f);
  float lg[4], lbv[4];
  ld4(&lag[d], lg);
  ld4(&lab[d], lbv);
  float hp[4];
  sa = 0.f; sb = 0.f;
#pragma unroll
  for (int j = 0; j < 4; ++j) {
    float a = (t[j] - mean) * rstd * lg[j] + lbv[j];
    hp[j] = xv[j] + a;
    sa += hp[j];
    sb += hp[j] * hp[j];
  }
  bsum2(sa, sb, sred, tid);
  float mean2 = sa * (1.f / 1024.f);
  float rstd2 = rsqrtf(sb * (1.f / 1024.f) - mean2 * mean2 + 1e-5f);
  float g2[4], b2[4];
  ld4(&n1g[d], g2);
  ld4(&n1b[d], b2);
  union { u16 q[4]; uint2 u; } pk;
#pragma unroll
  for (int j = 0; j < 4; ++j) pk.q[j] = f2bf((hp[j] - mean2) * rstd2 * g2[j] + b2[j]);
  *(uint2*)&hb[row * 1024 + d] = pk.u;
}

__global__ __launch_bounds__(256) void final_k(const u16* __restrict__ h,
                                               const u16* __restrict__ f3,
                                               const u16* __restrict__ gt,
                                               const float* __restrict__ n2g,
                                               const float* __restrict__ n2b,
                                               float* __restrict__ out) {
  __shared__ float sred[8];
  const size_t row = blockIdx.x;
  const int tid = threadIdx.x, d = tid * 4;
  float hv[4], fv[4], gv[4];
  ld4bf(&h[row * 1024 + d], hv);
  ld4bf(&f3[row * 1024 + d], fv);
  ld4bf(&gt[row * 1024 + d], gv);
  float t[4], sa = 0.f, sb = 0.f;
#pragma unroll
  for (int j = 0; j < 4; ++j) {
    t[j] = hv[j] + fv[j] * gv[j];
    sa += t[j];
    sb += t[j] * t[j];
  }
  bsum2(sa, sb, sred, tid);
  float mean = sa * (1.f / 1024.f);
  float rstd = rsqrtf(sb * (1.f / 1024.f) - mean * mean + 1e-5f);
  float g2[4], b2[4];
  ld4(&n2g[d], g2);
  ld4(&n2b[d], b2);
  float o[4];
#pragma unroll
  for (int j = 0; j < 4; ++j) o[j] = (t[j] - mean) * rstd * g2[j] + b2[j];
  *(float4*)&out[row * 1024 + d] = make_float4(o[0], o[1], o[2], o[3]);
}

// ---------------------------------------------------------------- launcher
extern "C" void kernel_launch(void* const* d_in, const int* in_sizes, int n_in,
                              void* d_out, int out_size, void* d_ws, size_t ws_size,
                              hipStream_t stream) {
  (void)in_sizes; (void)n_in; (void)out_size;
  const float* x   = (const float*)d_in[0];
  const float* Wq  = (const float*)d_in[1];
  const float* bq  = (const float*)d_in[2];
  const float* Wk  = (const float*)d_in[3];
  const float* bk  = (const float*)d_in[4];
  const float* Wv  = (const float*)d_in[5];
  const float* bv  = (const float*)d_in[6];
  const float* Wo  = (const float*)d_in[7];
  const float* bo  = (const float*)d_in[8];
  const float* cw  = (const float*)d_in[9];
  const float* cb  = (const float*)d_in[10];
  const float* lag = (const float*)d_in[11];
  const float* lab = (const float*)d_in[12];
  const float* W1  = (const float*)d_in[13];
  const float* b1  = (const float*)d_in[14];
  const float* W2  = (const float*)d_in[15];
  const float* b2  = (const float*)d_in[16];
  const float* W3  = (const float*)d_in[17];
  const float* b3  = (const float*)d_in[18];
  const float* Wg  = (const float*)d_in[19];
  const float* bg  = (const float*)d_in[20];
  const float* n1g = (const float*)d_in[21];
  const float* n1b = (const float*)d_in[22];
  const float* n2g = (const float*)d_in[23];
  const float* n2b = (const float*)d_in[24];

  const size_t MB = 1024ull * 1024ull;
  if (ws_size < 122 * MB) {
    sentinel_k<<<1, 64, 0, stream>>>((float*)d_out, (float)ws_size);
    return;
  }
  char* ws = (char*)d_ws;
  char* dob = (char*)d_out;
  u16* WoT   = (u16*)(ws + 0 * MB);
  u16* WgT   = (u16*)(ws + 2 * MB);
  u16* W1T   = (u16*)(ws + 4 * MB);
  u16* W2T   = (u16*)(ws + 12 * MB);
  u16* W3T   = (u16*)(ws + 44 * MB);
  u16* WqkvT = (u16*)(ws + 52 * MB);
  float* bqkv = (float*)(dob + 28 * MB);
  u16* xb    = (u16*)(ws + 58 * MB);
  u16* QKV   = (u16*)(ws + 74 * MB);
  u16* hb    = (u16*)(ws + 74 * MB);
  u16* f1h   = (u16*)(ws + 90 * MB);
  u16* gate  = (u16*)(ws + 90 * MB);
  u16* G     = xb;
  u16* f3    = xb;
  u16* Vt    = (u16*)dob;
  u16* globb = (u16*)(dob + 16 * MB);
  u16* f2h   = (u16*)dob;

  // ---- prep
  cast_k<<<4096, 256, 0, stream>>>(x, xb, (size_t)8192 * 1024);
  tcast5_k<<<dim3(16, 16, 5), 256, 0, stream>>>(Wq, Wk, Wv, Wo, Wg,
                                                WqkvT, WqkvT + 1024 * 1024,
                                                WqkvT + 2048 * 1024, WoT, WgT);
  tcast_k<<<dim3(16, 64), 256, 0, stream>>>(W1, W1T, 1024, 4096);
  tcast_k<<<dim3(64, 64), 256, 0, stream>>>(W2, W2T, 4096, 4096);
  tcast_k<<<dim3(64, 16), 256, 0, stream>>>(W3, W3T, 4096, 1024);
  catbias_k<<<12, 256, 0, stream>>>(bq, bk, bv, bqkv);

  // ---- attention block
  // QKV on gemm2 (R19): 1536 wg at 2 blocks/CU = 3 exact dispatch waves;
  // gemm8's 384 wg at 1/CU ran as 256+128 (half-idle tail wave).
  gemm2_k<0, 1><<<dim3(64, 24), 256, 0, stream>>>(xb, WqkvT, bqkv, QKV, 8192, 3072, 1024, 1.0f);
  tv_k<<<dim3(128, 16), 256, 0, stream>>>(QKV + 2048, Vt, 3072);
  attn_k<<<dim3(8, 128), 256, 0, stream>>>(QKV, QKV + 1024, Vt, globb, 3072);
  gemm2_k<0, 1><<<dim3(64, 8), 256, 0, stream>>>(globb, WoT, bo, G, 8192, 1024, 1024, 1.0f);
  post_attn_k<<<8192, 256, 0, stream>>>(x, G, cw, cb, lag, lab, n1g, n1b, hb);

  // ---- FFN in 2 M-halves of 4096
  for (int hf = 0; hf < 2; ++hf) {
    const size_t M0 = (size_t)hf * 4096;
    gemm8_k<4, 1, 1><<<dim3(16, 16), 512, 0, stream>>>(hb + M0 * 1024, W1T, b1, f1h,
                                                       4096, 4096, 1024, 1.0f);
    gemm8_k<4, 1, 1><<<dim3(16, 16), 512, 0, stream>>>(f1h, W2T, b2, f2h,
                                                       4096, 4096, 4096, 1.0f);
    gemm2_k<0, 1><<<dim3(32, 8), 256, 0, stream>>>(f2h, W3T, b3, f3 + M0 * 1024,
                                                   4096, 1024, 4096, 1.0f);
  }
  gemm2_k<2, 1><<<dim3(64, 8), 256, 0, stream>>>(hb, WgT, bg, gate, 8192, 1024, 1024, 1.0f);
  final_k<<<8192, 256, 0, stream>>>(hb, f3, gate, n2g, n2b, (float*)d_out);
}